// Round 7
// baseline (253.113 us; speedup 1.0000x reference)
//
#include <hip/hip_runtime.h>
#include <cstdint>

#define DIM   768
#define HEADS 12
#define HDIM  64
#define BATCH 4
#define SEQ   2048
#define MROWS (BATCH*SEQ)   // 8192

typedef __bf16 bf16;
typedef __bf16 bf16x4_t __attribute__((ext_vector_type(4)));
typedef __bf16 bf16x8_t __attribute__((ext_vector_type(8)));
typedef float  f32x4_t  __attribute__((ext_vector_type(4)));
typedef float  f32x16_t __attribute__((ext_vector_type(16)));

// ---------------- fp32 -> bf16 casts ----------------
__global__ void cast_bf16_kernel(const float* __restrict__ src, bf16* __restrict__ dst, int n4) {
    int i = blockIdx.x * blockDim.x + threadIdx.x;
    if (i >= n4) return;
    const float4 v = reinterpret_cast<const float4*>(src)[i];
    bf16x4_t o;
    o[0] = (bf16)v.x; o[1] = (bf16)v.y; o[2] = (bf16)v.z; o[3] = (bf16)v.w;
    reinterpret_cast<bf16x4_t*>(dst)[i] = o;
}

__global__ void cast_w4_kernel(const float* __restrict__ s0, const float* __restrict__ s1,
                               const float* __restrict__ s2, const float* __restrict__ s3,
                               bf16* __restrict__ d0, bf16* __restrict__ d1,
                               bf16* __restrict__ d2, bf16* __restrict__ d3, int n4) {
    int i = blockIdx.x * blockDim.x + threadIdx.x;
    if (i >= n4) return;
    int y = blockIdx.y;
    const float* src = (y == 0) ? s0 : (y == 1) ? s1 : (y == 2) ? s2 : s3;
    bf16* dst        = (y == 0) ? d0 : (y == 1) ? d1 : (y == 2) ? d2 : d3;
    const float4 v = reinterpret_cast<const float4*>(src)[i];
    bf16x4_t o;
    o[0] = (bf16)v.x; o[1] = (bf16)v.y; o[2] = (bf16)v.z; o[3] = (bf16)v.w;
    reinterpret_cast<bf16x4_t*>(dst)[i] = o;
}

// async global->LDS, 16B per lane. LDS dest is wave-uniform base + lane*16.
__device__ __forceinline__ void gload_lds16(const bf16* g, bf16* l) {
    __builtin_amdgcn_global_load_lds((const __attribute__((address_space(1))) void*)g,
                                     (__attribute__((address_space(3))) void*)l, 16, 0, 0);
}

// chunk swizzle for BK=32 rows (4 chunks of 16B): <=2-way bank residue on b128 reads
__device__ __forceinline__ int swz4(int row) { return (row & 3) ^ ((row >> 2) & 3); }

// ---------------- merged projection GEMM v4: prefetch + dbuf (BK=32, 24 phases) ---------
// z=0 -> Q (pre-scaled by log2(e)/8); z=1 -> K; z=2 -> Vt [768][8192] with the
// 4-sample-piece involution {0,2,1,3} per 16-sample group (direct attn V-frags).
__global__ __launch_bounds__(256, 3) void qkvv_gemm(
        const bf16* __restrict__ X,
        const bf16* __restrict__ Wq, const bf16* __restrict__ Wk, const bf16* __restrict__ Wv,
        bf16* __restrict__ Q, bf16* __restrict__ Kd, bf16* __restrict__ Vt)
{
    __shared__ __align__(16) bf16 SM[2][2][128 * 32];   // [buf][A|B][row*32] = 32KB
    const int tid  = threadIdx.x;

    // XCD-chunked bijective remap (nwg=1152, chunk=144)
    const int d  = blockIdx.x + 6 * blockIdx.y + 384 * blockIdx.z;
    const int L  = (d & 7) * 144 + (d >> 3);
    const int z  = L / 384;
    const int rem = L % 384;
    const int m0 = (rem % 6) * 128;   // dfull
    const int n0 = (rem / 6) * 128;   // sample

    const bf16* Ap = (z == 0) ? Wq : (z == 1 ? Wk : Wv);
    const int lane = tid & 63;
    const int w    = tid >> 6;
    const int wm   = (w & 1) * 64, wn = (w >> 1) * 64;
    const int lr   = lane & 15, quad = lane >> 4;

    // staging: 512 A-chunks + 512 B-chunks per phase, 2+2 per thread, linear LDS dest
    const int sr1 = tid >> 2, sc1 = tid & 3;
    const int sr2 = (tid + 256) >> 2;
    const int g1 = sc1 ^ swz4(sr1);
    const int g2 = sc1 ^ swz4(sr2);

    f32x4_t acc[4][4] = {};

    {   // prologue: stage phase 0 into buf 0
        gload_lds16(Ap + (size_t)(m0 + sr1) * DIM + g1 * 8, &SM[0][0][tid * 8]);
        gload_lds16(X  + (size_t)(n0 + sr1) * DIM + g1 * 8, &SM[0][1][tid * 8]);
        gload_lds16(Ap + (size_t)(m0 + sr2) * DIM + g2 * 8, &SM[0][0][(tid + 256) * 8]);
        gload_lds16(X  + (size_t)(n0 + sr2) * DIM + g2 * 8, &SM[0][1][(tid + 256) * 8]);
    }
    __syncthreads();

    int buf = 0;
    for (int p = 0; p < DIM / 32; ++p) {
        if (p + 1 < DIM / 32) {     // prefetch phase p+1 into buf^1 (sealed by this phase's barrier)
            int kk = (p + 1) * 32;
            gload_lds16(Ap + (size_t)(m0 + sr1) * DIM + kk + g1 * 8, &SM[buf ^ 1][0][tid * 8]);
            gload_lds16(X  + (size_t)(n0 + sr1) * DIM + kk + g1 * 8, &SM[buf ^ 1][1][tid * 8]);
            gload_lds16(Ap + (size_t)(m0 + sr2) * DIM + kk + g2 * 8, &SM[buf ^ 1][0][(tid + 256) * 8]);
            gload_lds16(X  + (size_t)(n0 + sr2) * DIM + kk + g2 * 8, &SM[buf ^ 1][1][(tid + 256) * 8]);
        }
        bf16x8_t af[4], bfr[4];
        #pragma unroll
        for (int i = 0; i < 4; ++i) {
            int row = wm + i * 16 + lr;
            af[i] = *reinterpret_cast<const bf16x8_t*>(&SM[buf][0][row * 32 + (quad ^ swz4(row)) * 8]);
        }
        #pragma unroll
        for (int j = 0; j < 4; ++j) {
            int row = wn + j * 16 + lr;
            bfr[j] = *reinterpret_cast<const bf16x8_t*>(&SM[buf][1][row * 32 + (quad ^ swz4(row)) * 8]);
        }
        #pragma unroll
        for (int i = 0; i < 4; ++i)
            #pragma unroll
            for (int j = 0; j < 4; ++j)
                acc[i][j] = __builtin_amdgcn_mfma_f32_16x16x32_bf16(af[i], bfr[j], acc[i][j], 0, 0, 0);
        __syncthreads();            // drains vmcnt (prefetch) + seals buf swap
        buf ^= 1;
    }

    if (z == 2) {
        // Stage C-tile (32KB = all of SM) with piece involution, then b128 row stores.
        bf16* CT = &SM[0][0][0];
        #pragma unroll
        for (int i = 0; i < 4; ++i) {
            int ml = wm + i * 16 + quad * 4;
            #pragma unroll
            for (int j = 0; j < 4; ++j) {
                int p   = lr >> 2;
                int pp  = ((p & 1) << 1) | (p >> 1);             // 0,2,1,3
                int nl  = wn + j * 16 + (pp << 2) + (lr & 3);
                #pragma unroll
                for (int r = 0; r < 4; ++r)
                    CT[(ml + r) * 128 + nl] = (bf16)acc[i][j][r];
            }
        }
        __syncthreads();
        const int rr = tid >> 4, cc = tid & 15;
        #pragma unroll
        for (int rnd = 0; rnd < 8; ++rnd) {
            int ml = rnd * 16 + rr;
            *reinterpret_cast<bf16x8_t*>(&Vt[(size_t)(m0 + ml) * MROWS + n0 + cc * 8]) =
                *reinterpret_cast<const bf16x8_t*>(&CT[ml * 128 + cc * 8]);
        }
    } else {
        const float sc = (z == 0) ? 0.18033688011112042f : 1.0f;   // log2(e)/8 into Q
        bf16* dst = (z == 0) ? Q : Kd;
        #pragma unroll
        for (int i = 0; i < 4; ++i) {
            int mb = m0 + wm + i * 16 + quad * 4;
            int h  = mb >> 6, d0 = mb & 63;
            #pragma unroll
            for (int j = 0; j < 4; ++j) {
                int sample = n0 + wn + j * 16 + lr;
                int b = sample >> 11, srow = sample & 2047;
                bf16x4_t o;
                #pragma unroll
                for (int r = 0; r < 4; ++r)
                    o[r] = (bf16)(acc[i][j][r] * sc);
                *reinterpret_cast<bf16x4_t*>(
                    &dst[(((size_t)b * HEADS + h) * SEQ + srow) * HDIM + d0]) = o;
            }
        }
    }
}

// ---------------- output projection GEMM v2: prefetch + dbuf (BK=32, 24 phases) --------
__global__ __launch_bounds__(256, 4) void out_gemm(
        const bf16* __restrict__ A,       // [8192,768]
        const bf16* __restrict__ W,       // [768,768]
        const float* __restrict__ bias,
        float* __restrict__ out)          // [8192,768] f32
{
    __shared__ __align__(16) bf16 SA[2][64 * 32];    // 2x4KB
    __shared__ __align__(16) bf16 SB[2][128 * 32];   // 2x8KB
    const int tid  = threadIdx.x;

    const int d  = blockIdx.x + 6 * blockIdx.y;   // 0..767
    const int L  = (d & 7) * 96 + (d >> 3);
    const int n0 = (L % 6) * 128;
    const int m0 = (L / 6) * 64;

    const int lane = tid & 63;
    const int w    = tid >> 6;
    const int wm   = (w & 1) * 32, wn = (w >> 1) * 64;
    const int lr   = lane & 15, quad = lane >> 4;

    const int sr1 = tid >> 2, sc1 = tid & 3;       // A: 256 chunks (rows 0..63), 1/thread
    const int sr2 = (tid + 256) >> 2;              // B second half
    const int g1 = sc1 ^ swz4(sr1);
    const int g2 = sc1 ^ swz4(sr2);

    f32x4_t acc[2][4] = {};

    {   // prologue: phase 0 into buf 0
        gload_lds16(A + (size_t)(m0 + sr1) * DIM + g1 * 8, &SA[0][tid * 8]);
        gload_lds16(W + (size_t)(n0 + sr1) * DIM + g1 * 8, &SB[0][tid * 8]);
        gload_lds16(W + (size_t)(n0 + sr2) * DIM + g2 * 8, &SB[0][(tid + 256) * 8]);
    }
    __syncthreads();

    int buf = 0;
    for (int p = 0; p < DIM / 32; ++p) {
        if (p + 1 < DIM / 32) {
            int kk = (p + 1) * 32;
            gload_lds16(A + (size_t)(m0 + sr1) * DIM + kk + g1 * 8, &SA[buf ^ 1][tid * 8]);
            gload_lds16(W + (size_t)(n0 + sr1) * DIM + kk + g1 * 8, &SB[buf ^ 1][tid * 8]);
            gload_lds16(W + (size_t)(n0 + sr2) * DIM + kk + g2 * 8, &SB[buf ^ 1][(tid + 256) * 8]);
        }
        bf16x8_t af[2], bfr[4];
        #pragma unroll
        for (int i = 0; i < 2; ++i) {
            int row = wm + i * 16 + lr;
            af[i] = *reinterpret_cast<const bf16x8_t*>(&SA[buf][row * 32 + (quad ^ swz4(row)) * 8]);
        }
        #pragma unroll
        for (int j = 0; j < 4; ++j) {
            int row = wn + j * 16 + lr;
            bfr[j] = *reinterpret_cast<const bf16x8_t*>(&SB[buf][row * 32 + (quad ^ swz4(row)) * 8]);
        }
        #pragma unroll
        for (int i = 0; i < 2; ++i)
            #pragma unroll
            for (int j = 0; j < 4; ++j)
                acc[i][j] = __builtin_amdgcn_mfma_f32_16x16x32_bf16(af[i], bfr[j], acc[i][j], 0, 0, 0);
        __syncthreads();
        buf ^= 1;
    }

    #pragma unroll
    for (int i = 0; i < 2; ++i) {
        int mbase = m0 + wm + i * 16 + quad * 4;
        #pragma unroll
        for (int j = 0; j < 4; ++j) {
            int n = n0 + wn + j * 16 + lr;
            float bv = bias[n];
            #pragma unroll
            for (int r = 0; r < 4; ++r) {
                int m = mbase + r;
                out[(size_t)m * DIM + n] = acc[i][j][r] + bv;
            }
        }
    }
}

// ---------------- flash attention v11: K direct global->reg, V-only LDS ----------------
// v10's LDS pipe was ~47% busy (16 b128/iter/wave), half of it the K path. The K
// MFMA A-fragment is contiguous 16B per lane in Kd's natural layout
// (K[kc*32+l31][16g+8hw..+7]), and the K tile is L1/L2-resident (XCD swizzle) --
// so load kf straight into registers with one-iteration lookahead: issue kf(t+1)
// right after QK(t) consumed kf(t); PV(t-1)+exp(t)+barrier (~1000cyc) hide the
// ~200cyc L2 hit. Removes 8 ds_read + 2 gload_lds per iter, K dbuf (LDS 40->24KB),
// and the QK->lgkmcnt dependency. V stays LDS-staged (bad global stride).
__global__ __launch_bounds__(256, 3) void attn_kernel(
        const bf16* __restrict__ Q, const bf16* __restrict__ Kd,
        const bf16* __restrict__ Vt, bf16* __restrict__ Ab)
{
    __shared__ __align__(16) bf16 SH[3 * 64 * 64];   // V tribuf (3x8KB); [1..2] = Q staging
    bf16* Vb = SH;

    const int tid  = threadIdx.x;

    // XCD-chunked bijective remap (nwg=768, chunk=96)
    const int dd = blockIdx.x + 16 * blockIdx.y;   // 0..767
    const int L  = (dd & 7) * 96 + (dd >> 3);
    const int bh = L >> 4;
    const int q0 = (L & 15) * 128;

    const int b    = bh / HEADS, h = bh % HEADS;
    const int lane = tid & 63, w = tid >> 6;
    const int l31  = lane & 31, hw = lane >> 5;
    const int wq   = w * 32;

    const size_t qkbase = (size_t)bh * SEQ * HDIM;
    const size_t vbase  = (size_t)h * HDIM * MROWS + (size_t)b * SEQ;

    const int src_row  = tid >> 3, src_ch = tid & 7;
    const int src_gch  = src_ch ^ (src_row & 7);
    const int src_row2 = (tid + 256) >> 3;
    const int src_gch2 = src_ch ^ (src_row2 & 7);
    const int loff1 = src_row  * 64 + src_ch * 8;
    const int loff2 = src_row2 * 64 + src_ch * 8;

    {   // Q (16KB) -> Vb[1..2] (consumed into qf before iter0's V(1) prefetch lands there)
        bf16* Qst = Vb + 4096;
        #pragma unroll
        for (int i = 0; i < 4; ++i) {
            int c = tid + i * 256;
            int row = c >> 3, ch = c & 7;
            int gch = ch ^ (row & 7);
            gload_lds16(Q + qkbase + (size_t)(q0 + row) * HDIM + gch * 8, Qst + row * 64 + ch * 8);
        }
    }

    const bf16* vp1 = Vt + vbase + (size_t)src_row  * MROWS + src_gch  * 8;
    const bf16* vp2 = Vt + vbase + (size_t)src_row2 * MROWS + src_gch2 * 8;
    const ptrdiff_t vstep = 64;

    gload_lds16(vp1, Vb + loff1); gload_lds16(vp2, Vb + loff2);
    __syncthreads();

    bf16x8_t qf[4];
    {
        const bf16* Qst = Vb + 4096;
        int row = wq + l31;
        #pragma unroll
        for (int g = 0; g < 4; ++g) {
            int ch = (2 * g + hw) ^ (row & 7);
            qf[g] = *reinterpret_cast<const bf16x8_t*>(&Qst[row * 64 + ch * 8]);
        }
    }
    __syncthreads();

    // per-lane K base: lane (l31,hw) reads K[seq = it*64 + kc*32 + l31][16g+8hw..+7]
    const bf16* kl = Kd + qkbase + (size_t)l31 * HDIM + hw * 8;

    bf16x8_t kf[2][4];
    #pragma unroll
    for (int kc = 0; kc < 2; ++kc)
        #pragma unroll
        for (int g = 0; g < 4; ++g)
            kf[kc][g] = *reinterpret_cast<const bf16x8_t*>(kl + kc * 2048 + g * 16);

    f32x16_t oacc[2] = {};
    f32x16_t rsacc  = {};
    bf16x8_t pk[4];
    bf16x8_t ones8;
    #pragma unroll
    for (int i = 0; i < 8; ++i) ones8[i] = (bf16)1.0f;

    int vprev = 2, vcur = 0, vnext = 1;
    const int NT = SEQ / 64;

    for (int it = 0; it < NT; ++it) {
        if (it + 1 < NT) {   // stage V(t+1)
            const ptrdiff_t g = (ptrdiff_t)(it + 1);
            bf16* vd = Vb + vnext * 4096;
            gload_lds16(vp1 + g * vstep, vd + loff1);
            gload_lds16(vp2 + g * vstep, vd + loff2);
        }

        // QK(t) from registers
        f32x16_t sacc[2] = {};
        __builtin_amdgcn_s_setprio(1);
        #pragma unroll
        for (int kc = 0; kc < 2; ++kc)
            #pragma unroll
            for (int g = 0; g < 4; ++g)
                sacc[kc] = __builtin_amdgcn_mfma_f32_32x32x16_bf16(kf[kc][g], qf[g], sacc[kc], 0, 0, 0);
        __builtin_amdgcn_s_setprio(0);

        // issue kf(t+1) now (WAR on kf resolved at MFMA issue); lands during PV+exp+barrier
        if (it + 1 < NT) {
            const bf16* kn = kl + (size_t)(it + 1) * 4096;
            #pragma unroll
            for (int kc = 0; kc < 2; ++kc)
                #pragma unroll
                for (int g = 0; g < 4; ++g)
                    kf[kc][g] = *reinterpret_cast<const bf16x8_t*>(kn + kc * 2048 + g * 16);
        }

        if (it > 0) {   // PV(t-1) + rsacc(t-1) with pk from previous iteration
            const bf16* Vs = Vb + vprev * 4096;
            __builtin_amdgcn_s_setprio(1);
            #pragma unroll
            for (int dc = 0; dc < 2; ++dc) {
                int row = dc * 32 + l31;
                #pragma unroll
                for (int kg = 0; kg < 4; ++kg) {
                    int myc = (2 * kg + hw) ^ (row & 7);
                    bf16x8_t bb = *reinterpret_cast<const bf16x8_t*>(&Vs[row * 64 + myc * 8]);
                    oacc[dc] = __builtin_amdgcn_mfma_f32_32x32x16_bf16(pk[kg], bb, oacc[dc], 0, 0, 0);
                }
            }
            #pragma unroll
            for (int kg = 0; kg < 4; ++kg)
                rsacc = __builtin_amdgcn_mfma_f32_32x32x16_bf16(pk[kg], ones8, rsacc, 0, 0, 0);
            __builtin_amdgcn_s_setprio(0);
        }

        #pragma unroll
        for (int kg = 0; kg < 4; ++kg) {
            #pragma unroll
            for (int j = 0; j < 8; ++j)
                pk[kg][j] = (bf16)__builtin_amdgcn_exp2f(sacc[kg >> 1][(kg & 1) * 8 + j]);
        }

        __syncthreads();
        int tmp = vprev; vprev = vcur; vcur = vnext; vnext = tmp;
    }

    {   // epilogue: PV(last) + rsacc(last)
        const bf16* Vs = Vb + vprev * 4096;
        #pragma unroll
        for (int dc = 0; dc < 2; ++dc) {
            int row = dc * 32 + l31;
            #pragma unroll
            for (int kg = 0; kg < 4; ++kg) {
                int myc = (2 * kg + hw) ^ (row & 7);
                bf16x8_t bb = *reinterpret_cast<const bf16x8_t*>(&Vs[row * 64 + myc * 8]);
                oacc[dc] = __builtin_amdgcn_mfma_f32_32x32x16_bf16(pk[kg], bb, oacc[dc], 0, 0, 0);
            }
        }
        #pragma unroll
        for (int kg = 0; kg < 4; ++kg)
            rsacc = __builtin_amdgcn_mfma_f32_32x32x16_bf16(pk[kg], ones8, rsacc, 0, 0, 0);
    }

    float inv[16];
    #pragma unroll
    for (int r = 0; r < 16; ++r)
        inv[r] = 1.0f / rsacc[r];
    #pragma unroll
    for (int dc = 0; dc < 2; ++dc) {
        int d = dc * 32 + l31;
        #pragma unroll
        for (int r = 0; r < 16; ++r) {
            int q = q0 + wq + (r & 3) + 8 * (r >> 2) + 4 * hw;
            Ab[((size_t)b * SEQ + q) * DIM + h * HDIM + d] = (bf16)(oacc[dc][r] * inv[r]);
        }
    }
}

extern "C" void kernel_launch(void* const* d_in, const int* in_sizes, int n_in,
                              void* d_out, int out_size, void* d_ws, size_t ws_size,
                              hipStream_t stream) {
    (void)in_sizes; (void)n_in; (void)out_size; (void)ws_size;
    const float* x  = (const float*)d_in[0];
    const float* Wq = (const float*)d_in[1];
    const float* Wk = (const float*)d_in[2];
    const float* Wv = (const float*)d_in[3];
    const float* Wp = (const float*)d_in[4];
    const float* bp = (const float*)d_in[5];
    float* out = (float*)d_out;

    char* ws = (char*)d_ws;
    size_t off = 0;
    auto alloc = [&](size_t bytes) {
        void* p = ws + off;
        off += (bytes + 255) & ~(size_t)255;
        return p;
    };
    const size_t big = (size_t)MROWS * DIM * sizeof(bf16);
    const size_t wsz = (size_t)DIM * DIM * sizeof(bf16);
    bf16* Xb  = (bf16*)alloc(big);
    bf16* Qb  = (bf16*)alloc(big);
    bf16* Kb  = (bf16*)alloc(big);
    bf16* Vtb = (bf16*)alloc(big);
    bf16* Wqb = (bf16*)alloc(wsz);
    bf16* Wkb = (bf16*)alloc(wsz);
    bf16* Wvb = (bf16*)alloc(wsz);
    bf16* Wpb = (bf16*)alloc(wsz);
    bf16* Ab  = Xb;   // Xb dead after projections

    const int x4 = MROWS * DIM / 4;
    cast_bf16_kernel<<<(x4 + 255) / 256, 256, 0, stream>>>(x, Xb, x4);
    const int w4 = DIM * DIM / 4;
    cast_w4_kernel<<<dim3((w4 + 255) / 256, 4), 256, 0, stream>>>(
        Wq, Wk, Wv, Wp, Wqb, Wkb, Wvb, Wpb, w4);

    qkvv_gemm<<<dim3(DIM / 128, MROWS / 128, 3), 256, 0, stream>>>(
        Xb, Wqb, Wkb, Wvb, Qb, Kb, Vtb);

    attn_kernel<<<dim3(SEQ / 128, BATCH * HEADS), 256, 0, stream>>>(Qb, Kb, Vtb, Ab);

    out_gemm<<<dim3(DIM / 128, MROWS / 64), 256, 0, stream>>>(Ab, Wpb, bp, out);
}

// Round 8
// 239.914 us; speedup vs baseline: 1.0550x; 1.0550x over previous
//
#include <hip/hip_runtime.h>
#include <cstdint>

#define DIM   768
#define HEADS 12
#define HDIM  64
#define BATCH 4
#define SEQ   2048
#define MROWS (BATCH*SEQ)   // 8192

typedef __bf16 bf16;
typedef __bf16 bf16x4_t __attribute__((ext_vector_type(4)));
typedef __bf16 bf16x8_t __attribute__((ext_vector_type(8)));
typedef float  f32x4_t  __attribute__((ext_vector_type(4)));
typedef float  f32x16_t __attribute__((ext_vector_type(16)));

// ---------------- fp32 -> bf16 casts ----------------
__global__ void cast_bf16_kernel(const float* __restrict__ src, bf16* __restrict__ dst, int n4) {
    int i = blockIdx.x * blockDim.x + threadIdx.x;
    if (i >= n4) return;
    const float4 v = reinterpret_cast<const float4*>(src)[i];
    bf16x4_t o;
    o[0] = (bf16)v.x; o[1] = (bf16)v.y; o[2] = (bf16)v.z; o[3] = (bf16)v.w;
    reinterpret_cast<bf16x4_t*>(dst)[i] = o;
}

__global__ void cast_w4_kernel(const float* __restrict__ s0, const float* __restrict__ s1,
                               const float* __restrict__ s2, const float* __restrict__ s3,
                               bf16* __restrict__ d0, bf16* __restrict__ d1,
                               bf16* __restrict__ d2, bf16* __restrict__ d3, int n4) {
    int i = blockIdx.x * blockDim.x + threadIdx.x;
    if (i >= n4) return;
    int y = blockIdx.y;
    const float* src = (y == 0) ? s0 : (y == 1) ? s1 : (y == 2) ? s2 : s3;
    bf16* dst        = (y == 0) ? d0 : (y == 1) ? d1 : (y == 2) ? d2 : d3;
    const float4 v = reinterpret_cast<const float4*>(src)[i];
    bf16x4_t o;
    o[0] = (bf16)v.x; o[1] = (bf16)v.y; o[2] = (bf16)v.z; o[3] = (bf16)v.w;
    reinterpret_cast<bf16x4_t*>(dst)[i] = o;
}

// async global->LDS, 16B per lane. LDS dest is wave-uniform base + lane*16.
__device__ __forceinline__ void gload_lds16(const bf16* g, bf16* l) {
    __builtin_amdgcn_global_load_lds((const __attribute__((address_space(1))) void*)g,
                                     (__attribute__((address_space(3))) void*)l, 16, 0, 0);
}

// chunk swizzle for BK=32 rows (4 chunks of 16B): <=2-way bank residue on b128 reads
__device__ __forceinline__ int swz4(int row) { return (row & 3) ^ ((row >> 2) & 3); }

// ---------------- merged projection GEMM v4: prefetch + dbuf (BK=32, 24 phases) ---------
// z=0 -> Q (pre-scaled by log2(e)/8); z=1 -> K; z=2 -> Vt [768][8192] with the
// 4-sample-piece involution {0,2,1,3} per 16-sample group (direct attn V-frags).
__global__ __launch_bounds__(256, 3) void qkvv_gemm(
        const bf16* __restrict__ X,
        const bf16* __restrict__ Wq, const bf16* __restrict__ Wk, const bf16* __restrict__ Wv,
        bf16* __restrict__ Q, bf16* __restrict__ Kd, bf16* __restrict__ Vt)
{
    __shared__ __align__(16) bf16 SM[2][2][128 * 32];   // [buf][A|B][row*32] = 32KB
    const int tid  = threadIdx.x;

    // XCD-chunked bijective remap (nwg=1152, chunk=144)
    const int d  = blockIdx.x + 6 * blockIdx.y + 384 * blockIdx.z;
    const int L  = (d & 7) * 144 + (d >> 3);
    const int z  = L / 384;
    const int rem = L % 384;
    const int m0 = (rem % 6) * 128;   // dfull
    const int n0 = (rem / 6) * 128;   // sample

    const bf16* Ap = (z == 0) ? Wq : (z == 1 ? Wk : Wv);
    const int lane = tid & 63;
    const int w    = tid >> 6;
    const int wm   = (w & 1) * 64, wn = (w >> 1) * 64;
    const int lr   = lane & 15, quad = lane >> 4;

    // staging: 512 A-chunks + 512 B-chunks per phase, 2+2 per thread, linear LDS dest
    const int sr1 = tid >> 2, sc1 = tid & 3;
    const int sr2 = (tid + 256) >> 2;
    const int g1 = sc1 ^ swz4(sr1);
    const int g2 = sc1 ^ swz4(sr2);

    f32x4_t acc[4][4] = {};

    {   // prologue: stage phase 0 into buf 0
        gload_lds16(Ap + (size_t)(m0 + sr1) * DIM + g1 * 8, &SM[0][0][tid * 8]);
        gload_lds16(X  + (size_t)(n0 + sr1) * DIM + g1 * 8, &SM[0][1][tid * 8]);
        gload_lds16(Ap + (size_t)(m0 + sr2) * DIM + g2 * 8, &SM[0][0][(tid + 256) * 8]);
        gload_lds16(X  + (size_t)(n0 + sr2) * DIM + g2 * 8, &SM[0][1][(tid + 256) * 8]);
    }
    __syncthreads();

    int buf = 0;
    for (int p = 0; p < DIM / 32; ++p) {
        if (p + 1 < DIM / 32) {     // prefetch phase p+1 into buf^1 (sealed by this phase's barrier)
            int kk = (p + 1) * 32;
            gload_lds16(Ap + (size_t)(m0 + sr1) * DIM + kk + g1 * 8, &SM[buf ^ 1][0][tid * 8]);
            gload_lds16(X  + (size_t)(n0 + sr1) * DIM + kk + g1 * 8, &SM[buf ^ 1][1][tid * 8]);
            gload_lds16(Ap + (size_t)(m0 + sr2) * DIM + kk + g2 * 8, &SM[buf ^ 1][0][(tid + 256) * 8]);
            gload_lds16(X  + (size_t)(n0 + sr2) * DIM + kk + g2 * 8, &SM[buf ^ 1][1][(tid + 256) * 8]);
        }
        bf16x8_t af[4], bfr[4];
        #pragma unroll
        for (int i = 0; i < 4; ++i) {
            int row = wm + i * 16 + lr;
            af[i] = *reinterpret_cast<const bf16x8_t*>(&SM[buf][0][row * 32 + (quad ^ swz4(row)) * 8]);
        }
        #pragma unroll
        for (int j = 0; j < 4; ++j) {
            int row = wn + j * 16 + lr;
            bfr[j] = *reinterpret_cast<const bf16x8_t*>(&SM[buf][1][row * 32 + (quad ^ swz4(row)) * 8]);
        }
        #pragma unroll
        for (int i = 0; i < 4; ++i)
            #pragma unroll
            for (int j = 0; j < 4; ++j)
                acc[i][j] = __builtin_amdgcn_mfma_f32_16x16x32_bf16(af[i], bfr[j], acc[i][j], 0, 0, 0);
        __syncthreads();            // drains vmcnt (prefetch) + seals buf swap
        buf ^= 1;
    }

    if (z == 2) {
        // Stage C-tile (32KB = all of SM) with piece involution, then b128 row stores.
        bf16* CT = &SM[0][0][0];
        #pragma unroll
        for (int i = 0; i < 4; ++i) {
            int ml = wm + i * 16 + quad * 4;
            #pragma unroll
            for (int j = 0; j < 4; ++j) {
                int p   = lr >> 2;
                int pp  = ((p & 1) << 1) | (p >> 1);             // 0,2,1,3
                int nl  = wn + j * 16 + (pp << 2) + (lr & 3);
                #pragma unroll
                for (int r = 0; r < 4; ++r)
                    CT[(ml + r) * 128 + nl] = (bf16)acc[i][j][r];
            }
        }
        __syncthreads();
        const int rr = tid >> 4, cc = tid & 15;
        #pragma unroll
        for (int rnd = 0; rnd < 8; ++rnd) {
            int ml = rnd * 16 + rr;
            *reinterpret_cast<bf16x8_t*>(&Vt[(size_t)(m0 + ml) * MROWS + n0 + cc * 8]) =
                *reinterpret_cast<const bf16x8_t*>(&CT[ml * 128 + cc * 8]);
        }
    } else {
        const float sc = (z == 0) ? 0.18033688011112042f : 1.0f;   // log2(e)/8 into Q
        bf16* dst = (z == 0) ? Q : Kd;
        #pragma unroll
        for (int i = 0; i < 4; ++i) {
            int mb = m0 + wm + i * 16 + quad * 4;
            int h  = mb >> 6, d0 = mb & 63;
            #pragma unroll
            for (int j = 0; j < 4; ++j) {
                int sample = n0 + wn + j * 16 + lr;
                int b = sample >> 11, srow = sample & 2047;
                bf16x4_t o;
                #pragma unroll
                for (int r = 0; r < 4; ++r)
                    o[r] = (bf16)(acc[i][j][r] * sc);
                *reinterpret_cast<bf16x4_t*>(
                    &dst[(((size_t)b * HEADS + h) * SEQ + srow) * HDIM + d0]) = o;
            }
        }
    }
}

// ---------------- output projection GEMM v2: prefetch + dbuf (BK=32, 24 phases) --------
__global__ __launch_bounds__(256, 4) void out_gemm(
        const bf16* __restrict__ A,       // [8192,768]
        const bf16* __restrict__ W,       // [768,768]
        const float* __restrict__ bias,
        float* __restrict__ out)          // [8192,768] f32
{
    __shared__ __align__(16) bf16 SA[2][64 * 32];    // 2x4KB
    __shared__ __align__(16) bf16 SB[2][128 * 32];   // 2x8KB
    const int tid  = threadIdx.x;

    const int d  = blockIdx.x + 6 * blockIdx.y;   // 0..767
    const int L  = (d & 7) * 96 + (d >> 3);
    const int n0 = (L % 6) * 128;
    const int m0 = (L / 6) * 64;

    const int lane = tid & 63;
    const int w    = tid >> 6;
    const int wm   = (w & 1) * 32, wn = (w >> 1) * 64;
    const int lr   = lane & 15, quad = lane >> 4;

    const int sr1 = tid >> 2, sc1 = tid & 3;       // A: 256 chunks (rows 0..63), 1/thread
    const int sr2 = (tid + 256) >> 2;              // B second half
    const int g1 = sc1 ^ swz4(sr1);
    const int g2 = sc1 ^ swz4(sr2);

    f32x4_t acc[2][4] = {};

    {   // prologue: phase 0 into buf 0
        gload_lds16(A + (size_t)(m0 + sr1) * DIM + g1 * 8, &SA[0][tid * 8]);
        gload_lds16(W + (size_t)(n0 + sr1) * DIM + g1 * 8, &SB[0][tid * 8]);
        gload_lds16(W + (size_t)(n0 + sr2) * DIM + g2 * 8, &SB[0][(tid + 256) * 8]);
    }
    __syncthreads();

    int buf = 0;
    for (int p = 0; p < DIM / 32; ++p) {
        if (p + 1 < DIM / 32) {
            int kk = (p + 1) * 32;
            gload_lds16(A + (size_t)(m0 + sr1) * DIM + kk + g1 * 8, &SA[buf ^ 1][tid * 8]);
            gload_lds16(W + (size_t)(n0 + sr1) * DIM + kk + g1 * 8, &SB[buf ^ 1][tid * 8]);
            gload_lds16(W + (size_t)(n0 + sr2) * DIM + kk + g2 * 8, &SB[buf ^ 1][(tid + 256) * 8]);
        }
        bf16x8_t af[2], bfr[4];
        #pragma unroll
        for (int i = 0; i < 2; ++i) {
            int row = wm + i * 16 + lr;
            af[i] = *reinterpret_cast<const bf16x8_t*>(&SA[buf][row * 32 + (quad ^ swz4(row)) * 8]);
        }
        #pragma unroll
        for (int j = 0; j < 4; ++j) {
            int row = wn + j * 16 + lr;
            bfr[j] = *reinterpret_cast<const bf16x8_t*>(&SB[buf][row * 32 + (quad ^ swz4(row)) * 8]);
        }
        #pragma unroll
        for (int i = 0; i < 2; ++i)
            #pragma unroll
            for (int j = 0; j < 4; ++j)
                acc[i][j] = __builtin_amdgcn_mfma_f32_16x16x32_bf16(af[i], bfr[j], acc[i][j], 0, 0, 0);
        __syncthreads();
        buf ^= 1;
    }

    #pragma unroll
    for (int i = 0; i < 2; ++i) {
        int mbase = m0 + wm + i * 16 + quad * 4;
        #pragma unroll
        for (int j = 0; j < 4; ++j) {
            int n = n0 + wn + j * 16 + lr;
            float bv = bias[n];
            #pragma unroll
            for (int r = 0; r < 4; ++r) {
                int m = mbase + r;
                out[(size_t)m * DIM + n] = acc[i][j][r] + bv;
            }
        }
    }
}

// ---------------- flash attention v12: QBLK=64/wave (2-wave blocks) ----------------
// v11 (K->reg) REVERTED: vmcnt drain in the loop, latency-bound at 23% MfmaUtil.
// K back in LDS dbuf. New lever: each wave owns 64 q-rows (2 q-groups), so each
// K/V b128 LDS read feeds TWO MFMAs -> LDS reads per MFMA halve (the LDS pipe was
// ~47% of the wall). Blocks are 128 threads x 2 waves; grid stays 768. Per-iter
// order: stage(t+1) | PV(t-1) (frees pk before sacc peaks) | QK(t) | exp -> pk.
// VGPR budget ~240: launch_bounds(128,1) caps at 256 (spill = fail signal).
__global__ __launch_bounds__(128, 1) void attn_kernel(
        const bf16* __restrict__ Q, const bf16* __restrict__ Kd,
        const bf16* __restrict__ Vt, bf16* __restrict__ Ab)
{
    __shared__ __align__(16) bf16 SH[5 * 64 * 64];   // K dbuf (2x8KB) + V tribuf (3x8KB)
    bf16* Kb = SH;
    bf16* Vb = SH + 2 * 4096;

    const int tid  = threadIdx.x;   // 0..127

    // XCD-chunked bijective remap (nwg=768, chunk=96)
    const int dd = blockIdx.x + 16 * blockIdx.y;   // 0..767
    const int L  = (dd & 7) * 96 + (dd >> 3);
    const int bh = L >> 4;
    const int q0 = (L & 15) * 128;

    const int b    = bh / HEADS, h = bh % HEADS;
    const int lane = tid & 63, w = tid >> 6;       // w in {0,1}
    const int l31  = lane & 31, hw = lane >> 5;
    const int wq   = w * 64;                       // wave q-base (64 rows/wave)

    const size_t qkbase = (size_t)bh * SEQ * HDIM;
    const size_t vbase  = (size_t)h * HDIM * MROWS + (size_t)b * SEQ;

    // staging: 512 chunks per 8KB tile, 4 per thread (128 threads)
    const int sch = tid & 7;
    int srow[4], loff[4];
    const bf16 *kp[4], *vp[4];
    #pragma unroll
    for (int j = 0; j < 4; ++j) {
        int c = tid + j * 128;
        srow[j] = c >> 3;                           // 0..63
        int gch = sch ^ (srow[j] & 7);
        loff[j] = srow[j] * 64 + sch * 8;
        kp[j] = Kd + qkbase + (size_t)srow[j] * HDIM  + gch * 8;
        vp[j] = Vt + vbase  + (size_t)srow[j] * MROWS + gch * 8;
    }
    const ptrdiff_t kstep = 64 * HDIM, vstep = 64;

    {   // Q (16KB, 128 rows) -> Vb[1..2]; 8 chunks per thread
        bf16* Qst = Vb + 4096;
        #pragma unroll
        for (int i = 0; i < 8; ++i) {
            int c = tid + i * 128;
            int row = c >> 3, ch = c & 7;
            int gch = ch ^ (row & 7);
            gload_lds16(Q + qkbase + (size_t)(q0 + row) * HDIM + gch * 8, Qst + row * 64 + ch * 8);
        }
    }

    // stage K(0), V(0)
    #pragma unroll
    for (int j = 0; j < 4; ++j) {
        gload_lds16(kp[j], Kb + loff[j]);
        gload_lds16(vp[j], Vb + loff[j]);
    }
    __syncthreads();

    bf16x8_t qf[2][4];
    {
        const bf16* Qst = Vb + 4096;
        #pragma unroll
        for (int qg = 0; qg < 2; ++qg) {
            int row = wq + qg * 32 + l31;
            #pragma unroll
            for (int g = 0; g < 4; ++g) {
                int ch = (2 * g + hw) ^ (row & 7);
                qf[qg][g] = *reinterpret_cast<const bf16x8_t*>(&Qst[row * 64 + ch * 8]);
            }
        }
    }
    __syncthreads();   // all waves done with Q before iter0 stages V(1) over it

    f32x16_t oacc[2][2] = {};
    f32x16_t rsacc[2]  = {};
    bf16x8_t pk[2][4];
    bf16x8_t ones8;
    #pragma unroll
    for (int i = 0; i < 8; ++i) ones8[i] = (bf16)1.0f;

    int vprev = 2, vcur = 0, vnext = 1;
    const int NT = SEQ / 64;

    for (int it = 0; it < NT; ++it) {
        if (it + 1 < NT) {   // stage K(t+1), V(t+1)
            bf16* kd = Kb + ((it + 1) & 1) * 4096;
            bf16* vd = Vb + vnext * 4096;
            #pragma unroll
            for (int j = 0; j < 4; ++j) {
                gload_lds16(kp[j] + (ptrdiff_t)(it + 1) * kstep, kd + loff[j]);
                gload_lds16(vp[j] + (ptrdiff_t)(it + 1) * vstep, vd + loff[j]);
            }
        }

        if (it > 0) {   // PV(t-1) + rsacc(t-1): consumes pk, frees it before sacc peaks
            const bf16* Vs = Vb + vprev * 4096;
            __builtin_amdgcn_s_setprio(1);
            #pragma unroll
            for (int dc = 0; dc < 2; ++dc) {
                int row = dc * 32 + l31;
                #pragma unroll
                for (int kg = 0; kg < 4; ++kg) {
                    int myc = (2 * kg + hw) ^ (row & 7);
                    bf16x8_t bb = *reinterpret_cast<const bf16x8_t*>(&Vs[row * 64 + myc * 8]);
                    oacc[0][dc] = __builtin_amdgcn_mfma_f32_32x32x16_bf16(pk[0][kg], bb, oacc[0][dc], 0, 0, 0);
                    oacc[1][dc] = __builtin_amdgcn_mfma_f32_32x32x16_bf16(pk[1][kg], bb, oacc[1][dc], 0, 0, 0);
                }
            }
            #pragma unroll
            for (int kg = 0; kg < 4; ++kg) {
                rsacc[0] = __builtin_amdgcn_mfma_f32_32x32x16_bf16(pk[0][kg], ones8, rsacc[0], 0, 0, 0);
                rsacc[1] = __builtin_amdgcn_mfma_f32_32x32x16_bf16(pk[1][kg], ones8, rsacc[1], 0, 0, 0);
            }
            __builtin_amdgcn_s_setprio(0);
        }

        // QK(t): each K fragment feeds both q-groups
        const bf16* Ks = Kb + (it & 1) * 4096;
        f32x16_t sacc[2][2] = {};
        __builtin_amdgcn_s_setprio(1);
        #pragma unroll
        for (int kc = 0; kc < 2; ++kc) {
            int row = kc * 32 + l31;
            #pragma unroll
            for (int g = 0; g < 4; ++g) {
                int ch = (2 * g + hw) ^ (row & 7);
                bf16x8_t af = *reinterpret_cast<const bf16x8_t*>(&Ks[row * 64 + ch * 8]);
                sacc[0][kc] = __builtin_amdgcn_mfma_f32_32x32x16_bf16(af, qf[0][g], sacc[0][kc], 0, 0, 0);
                sacc[1][kc] = __builtin_amdgcn_mfma_f32_32x32x16_bf16(af, qf[1][g], sacc[1][kc], 0, 0, 0);
            }
        }
        __builtin_amdgcn_s_setprio(0);

        #pragma unroll
        for (int qg = 0; qg < 2; ++qg)
            #pragma unroll
            for (int kg = 0; kg < 4; ++kg) {
                #pragma unroll
                for (int j = 0; j < 8; ++j)
                    pk[qg][kg][j] = (bf16)__builtin_amdgcn_exp2f(sacc[qg][kg >> 1][(kg & 1) * 8 + j]);
            }

        __syncthreads();
        int tmp = vprev; vprev = vcur; vcur = vnext; vnext = tmp;
    }

    {   // epilogue: PV(last) + rsacc(last)
        const bf16* Vs = Vb + vprev * 4096;
        #pragma unroll
        for (int dc = 0; dc < 2; ++dc) {
            int row = dc * 32 + l31;
            #pragma unroll
            for (int kg = 0; kg < 4; ++kg) {
                int myc = (2 * kg + hw) ^ (row & 7);
                bf16x8_t bb = *reinterpret_cast<const bf16x8_t*>(&Vs[row * 64 + myc * 8]);
                oacc[0][dc] = __builtin_amdgcn_mfma_f32_32x32x16_bf16(pk[0][kg], bb, oacc[0][dc], 0, 0, 0);
                oacc[1][dc] = __builtin_amdgcn_mfma_f32_32x32x16_bf16(pk[1][kg], bb, oacc[1][dc], 0, 0, 0);
            }
        }
        #pragma unroll
        for (int kg = 0; kg < 4; ++kg) {
            rsacc[0] = __builtin_amdgcn_mfma_f32_32x32x16_bf16(pk[0][kg], ones8, rsacc[0], 0, 0, 0);
            rsacc[1] = __builtin_amdgcn_mfma_f32_32x32x16_bf16(pk[1][kg], ones8, rsacc[1], 0, 0, 0);
        }
    }

    #pragma unroll
    for (int qg = 0; qg < 2; ++qg) {
        float inv[16];
        #pragma unroll
        for (int r = 0; r < 16; ++r)
            inv[r] = 1.0f / rsacc[qg][r];
        #pragma unroll
        for (int dc = 0; dc < 2; ++dc) {
            int d = dc * 32 + l31;
            #pragma unroll
            for (int r = 0; r < 16; ++r) {
                int q = q0 + wq + qg * 32 + (r & 3) + 8 * (r >> 2) + 4 * hw;
                Ab[((size_t)b * SEQ + q) * DIM + h * HDIM + d] = (bf16)(oacc[qg][dc][r] * inv[r]);
            }
        }
    }
}

extern "C" void kernel_launch(void* const* d_in, const int* in_sizes, int n_in,
                              void* d_out, int out_size, void* d_ws, size_t ws_size,
                              hipStream_t stream) {
    (void)in_sizes; (void)n_in; (void)out_size; (void)ws_size;
    const float* x  = (const float*)d_in[0];
    const float* Wq = (const float*)d_in[1];
    const float* Wk = (const float*)d_in[2];
    const float* Wv = (const float*)d_in[3];
    const float* Wp = (const float*)d_in[4];
    const float* bp = (const float*)d_in[5];
    float* out = (float*)d_out;

    char* ws = (char*)d_ws;
    size_t off = 0;
    auto alloc = [&](size_t bytes) {
        void* p = ws + off;
        off += (bytes + 255) & ~(size_t)255;
        return p;
    };
    const size_t big = (size_t)MROWS * DIM * sizeof(bf16);
    const size_t wsz = (size_t)DIM * DIM * sizeof(bf16);
    bf16* Xb  = (bf16*)alloc(big);
    bf16* Qb  = (bf16*)alloc(big);
    bf16* Kb  = (bf16*)alloc(big);
    bf16* Vtb = (bf16*)alloc(big);
    bf16* Wqb = (bf16*)alloc(wsz);
    bf16* Wkb = (bf16*)alloc(wsz);
    bf16* Wvb = (bf16*)alloc(wsz);
    bf16* Wpb = (bf16*)alloc(wsz);
    bf16* Ab  = Xb;   // Xb dead after projections

    const int x4 = MROWS * DIM / 4;
    cast_bf16_kernel<<<(x4 + 255) / 256, 256, 0, stream>>>(x, Xb, x4);
    const int w4 = DIM * DIM / 4;
    cast_w4_kernel<<<dim3((w4 + 255) / 256, 4), 256, 0, stream>>>(
        Wq, Wk, Wv, Wp, Wqb, Wkb, Wvb, Wpb, w4);

    qkvv_gemm<<<dim3(DIM / 128, MROWS / 128, 3), 256, 0, stream>>>(
        Xb, Wqb, Wkb, Wvb, Qb, Kb, Vtb);

    attn_kernel<<<dim3(SEQ / 128, BATCH * HEADS), 128, 0, stream>>>(Qb, Kb, Vtb, Ab);

    out_gemm<<<dim3(DIM / 128, MROWS / 64), 256, 0, stream>>>(Ab, Wpb, bp, out);
}

// Round 9
// 217.146 us; speedup vs baseline: 1.1656x; 1.1049x over previous
//
#include <hip/hip_runtime.h>
#include <cstdint>

#define DIM   768
#define HEADS 12
#define HDIM  64
#define BATCH 4
#define SEQ   2048
#define MROWS (BATCH*SEQ)   // 8192

typedef __bf16 bf16;
typedef __bf16 bf16x4_t __attribute__((ext_vector_type(4)));
typedef __bf16 bf16x8_t __attribute__((ext_vector_type(8)));
typedef float  f32x4_t  __attribute__((ext_vector_type(4)));
typedef float  f32x16_t __attribute__((ext_vector_type(16)));

#define X4   (MROWS * DIM / 4)          // 1572864 float4-groups for x
#define W4   (DIM * DIM / 4)            // 147456 per weight
#define ALL4 (X4 + 4 * W4)              // 2162688 total

// ---------------- merged fp32 -> bf16 cast (x + 4 weights, one launch) ----------------
__global__ void cast_all_kernel(const float* __restrict__ x,
                                const float* __restrict__ w0, const float* __restrict__ w1,
                                const float* __restrict__ w2, const float* __restrict__ w3,
                                bf16* __restrict__ xd,
                                bf16* __restrict__ d0, bf16* __restrict__ d1,
                                bf16* __restrict__ d2, bf16* __restrict__ d3) {
    int i = blockIdx.x * blockDim.x + threadIdx.x;
    if (i >= ALL4) return;
    const float* src; bf16* dst; int j;
    if (i < X4) { src = x; dst = xd; j = i; }
    else {
        int t = i - X4;  int y = t / W4;  j = t - y * W4;
        src = (y == 0) ? w0 : (y == 1) ? w1 : (y == 2) ? w2 : w3;
        dst = (y == 0) ? d0 : (y == 1) ? d1 : (y == 2) ? d2 : d3;
    }
    const float4 v = reinterpret_cast<const float4*>(src)[j];
    bf16x4_t o;
    o[0] = (bf16)v.x; o[1] = (bf16)v.y; o[2] = (bf16)v.z; o[3] = (bf16)v.w;
    reinterpret_cast<bf16x4_t*>(dst)[j] = o;
}

// async global->LDS, 16B per lane. LDS dest is wave-uniform base + lane*16.
__device__ __forceinline__ void gload_lds16(const bf16* g, bf16* l) {
    __builtin_amdgcn_global_load_lds((const __attribute__((address_space(1))) void*)g,
                                     (__attribute__((address_space(3))) void*)l, 16, 0, 0);
}

// chunk swizzle for BK=32 rows (4 chunks of 16B): <=2-way bank residue on b128 reads
__device__ __forceinline__ int swz4(int row) { return (row & 3) ^ ((row >> 2) & 3); }

// ---------------- merged projection GEMM v4: prefetch + dbuf (BK=32, 24 phases) ---------
// z=0 -> Q (pre-scaled by log2(e)/8); z=1 -> K; z=2 -> Vt [768][8192] with the
// 4-sample-piece involution {0,2,1,3} per 16-sample group (direct attn V-frags).
__global__ __launch_bounds__(256, 3) void qkvv_gemm(
        const bf16* __restrict__ X,
        const bf16* __restrict__ Wq, const bf16* __restrict__ Wk, const bf16* __restrict__ Wv,
        bf16* __restrict__ Q, bf16* __restrict__ Kd, bf16* __restrict__ Vt)
{
    __shared__ __align__(16) bf16 SM[2][2][128 * 32];   // [buf][A|B][row*32] = 32KB
    const int tid  = threadIdx.x;

    // XCD-chunked bijective remap (nwg=1152, chunk=144)
    const int d  = blockIdx.x + 6 * blockIdx.y + 384 * blockIdx.z;
    const int L  = (d & 7) * 144 + (d >> 3);
    const int z  = L / 384;
    const int rem = L % 384;
    const int m0 = (rem % 6) * 128;   // dfull
    const int n0 = (rem / 6) * 128;   // sample

    const bf16* Ap = (z == 0) ? Wq : (z == 1 ? Wk : Wv);
    const int lane = tid & 63;
    const int w    = tid >> 6;
    const int wm   = (w & 1) * 64, wn = (w >> 1) * 64;
    const int lr   = lane & 15, quad = lane >> 4;

    // staging: 512 A-chunks + 512 B-chunks per phase, 2+2 per thread, linear LDS dest
    const int sr1 = tid >> 2, sc1 = tid & 3;
    const int sr2 = (tid + 256) >> 2;
    const int g1 = sc1 ^ swz4(sr1);
    const int g2 = sc1 ^ swz4(sr2);

    f32x4_t acc[4][4] = {};

    {   // prologue: stage phase 0 into buf 0
        gload_lds16(Ap + (size_t)(m0 + sr1) * DIM + g1 * 8, &SM[0][0][tid * 8]);
        gload_lds16(X  + (size_t)(n0 + sr1) * DIM + g1 * 8, &SM[0][1][tid * 8]);
        gload_lds16(Ap + (size_t)(m0 + sr2) * DIM + g2 * 8, &SM[0][0][(tid + 256) * 8]);
        gload_lds16(X  + (size_t)(n0 + sr2) * DIM + g2 * 8, &SM[0][1][(tid + 256) * 8]);
    }
    __syncthreads();

    int buf = 0;
    for (int p = 0; p < DIM / 32; ++p) {
        if (p + 1 < DIM / 32) {     // prefetch phase p+1 into buf^1 (sealed by this phase's barrier)
            int kk = (p + 1) * 32;
            gload_lds16(Ap + (size_t)(m0 + sr1) * DIM + kk + g1 * 8, &SM[buf ^ 1][0][tid * 8]);
            gload_lds16(X  + (size_t)(n0 + sr1) * DIM + kk + g1 * 8, &SM[buf ^ 1][1][tid * 8]);
            gload_lds16(Ap + (size_t)(m0 + sr2) * DIM + kk + g2 * 8, &SM[buf ^ 1][0][(tid + 256) * 8]);
            gload_lds16(X  + (size_t)(n0 + sr2) * DIM + kk + g2 * 8, &SM[buf ^ 1][1][(tid + 256) * 8]);
        }
        bf16x8_t af[4], bfr[4];
        #pragma unroll
        for (int i = 0; i < 4; ++i) {
            int row = wm + i * 16 + lr;
            af[i] = *reinterpret_cast<const bf16x8_t*>(&SM[buf][0][row * 32 + (quad ^ swz4(row)) * 8]);
        }
        #pragma unroll
        for (int j = 0; j < 4; ++j) {
            int row = wn + j * 16 + lr;
            bfr[j] = *reinterpret_cast<const bf16x8_t*>(&SM[buf][1][row * 32 + (quad ^ swz4(row)) * 8]);
        }
        #pragma unroll
        for (int i = 0; i < 4; ++i)
            #pragma unroll
            for (int j = 0; j < 4; ++j)
                acc[i][j] = __builtin_amdgcn_mfma_f32_16x16x32_bf16(af[i], bfr[j], acc[i][j], 0, 0, 0);
        __syncthreads();            // drains vmcnt (prefetch) + seals buf swap
        buf ^= 1;
    }

    if (z == 2) {
        // Stage C-tile (32KB = all of SM) with piece involution, then b128 row stores.
        bf16* CT = &SM[0][0][0];
        #pragma unroll
        for (int i = 0; i < 4; ++i) {
            int ml = wm + i * 16 + quad * 4;
            #pragma unroll
            for (int j = 0; j < 4; ++j) {
                int p   = lr >> 2;
                int pp  = ((p & 1) << 1) | (p >> 1);             // 0,2,1,3
                int nl  = wn + j * 16 + (pp << 2) + (lr & 3);
                #pragma unroll
                for (int r = 0; r < 4; ++r)
                    CT[(ml + r) * 128 + nl] = (bf16)acc[i][j][r];
            }
        }
        __syncthreads();
        const int rr = tid >> 4, cc = tid & 15;
        #pragma unroll
        for (int rnd = 0; rnd < 8; ++rnd) {
            int ml = rnd * 16 + rr;
            *reinterpret_cast<bf16x8_t*>(&Vt[(size_t)(m0 + ml) * MROWS + n0 + cc * 8]) =
                *reinterpret_cast<const bf16x8_t*>(&CT[ml * 128 + cc * 8]);
        }
    } else {
        const float sc = (z == 0) ? 0.18033688011112042f : 1.0f;   // log2(e)/8 into Q
        bf16* dst = (z == 0) ? Q : Kd;
        #pragma unroll
        for (int i = 0; i < 4; ++i) {
            int mb = m0 + wm + i * 16 + quad * 4;
            int h  = mb >> 6, d0 = mb & 63;
            #pragma unroll
            for (int j = 0; j < 4; ++j) {
                int sample = n0 + wn + j * 16 + lr;
                int b = sample >> 11, srow = sample & 2047;
                bf16x4_t o;
                #pragma unroll
                for (int r = 0; r < 4; ++r)
                    o[r] = (bf16)(acc[i][j][r] * sc);
                *reinterpret_cast<bf16x4_t*>(
                    &dst[(((size_t)b * HEADS + h) * SEQ + srow) * HDIM + d0]) = o;
            }
        }
    }
}

// ---------------- output projection GEMM v2: prefetch + dbuf (BK=32, 24 phases) --------
__global__ __launch_bounds__(256, 4) void out_gemm(
        const bf16* __restrict__ A,       // [8192,768]
        const bf16* __restrict__ W,       // [768,768]
        const float* __restrict__ bias,
        float* __restrict__ out)          // [8192,768] f32
{
    __shared__ __align__(16) bf16 SA[2][64 * 32];    // 2x4KB
    __shared__ __align__(16) bf16 SB[2][128 * 32];   // 2x8KB
    const int tid  = threadIdx.x;

    const int d  = blockIdx.x + 6 * blockIdx.y;   // 0..767
    const int L  = (d & 7) * 96 + (d >> 3);
    const int n0 = (L % 6) * 128;
    const int m0 = (L / 6) * 64;

    const int lane = tid & 63;
    const int w    = tid >> 6;
    const int wm   = (w & 1) * 32, wn = (w >> 1) * 64;
    const int lr   = lane & 15, quad = lane >> 4;

    const int sr1 = tid >> 2, sc1 = tid & 3;       // A: 256 chunks (rows 0..63), 1/thread
    const int sr2 = (tid + 256) >> 2;              // B second half
    const int g1 = sc1 ^ swz4(sr1);
    const int g2 = sc1 ^ swz4(sr2);

    f32x4_t acc[2][4] = {};

    {   // prologue: phase 0 into buf 0
        gload_lds16(A + (size_t)(m0 + sr1) * DIM + g1 * 8, &SA[0][tid * 8]);
        gload_lds16(W + (size_t)(n0 + sr1) * DIM + g1 * 8, &SB[0][tid * 8]);
        gload_lds16(W + (size_t)(n0 + sr2) * DIM + g2 * 8, &SB[0][(tid + 256) * 8]);
    }
    __syncthreads();

    int buf = 0;
    for (int p = 0; p < DIM / 32; ++p) {
        if (p + 1 < DIM / 32) {
            int kk = (p + 1) * 32;
            gload_lds16(A + (size_t)(m0 + sr1) * DIM + kk + g1 * 8, &SA[buf ^ 1][tid * 8]);
            gload_lds16(W + (size_t)(n0 + sr1) * DIM + kk + g1 * 8, &SB[buf ^ 1][tid * 8]);
            gload_lds16(W + (size_t)(n0 + sr2) * DIM + kk + g2 * 8, &SB[buf ^ 1][(tid + 256) * 8]);
        }
        bf16x8_t af[2], bfr[4];
        #pragma unroll
        for (int i = 0; i < 2; ++i) {
            int row = wm + i * 16 + lr;
            af[i] = *reinterpret_cast<const bf16x8_t*>(&SA[buf][row * 32 + (quad ^ swz4(row)) * 8]);
        }
        #pragma unroll
        for (int j = 0; j < 4; ++j) {
            int row = wn + j * 16 + lr;
            bfr[j] = *reinterpret_cast<const bf16x8_t*>(&SB[buf][row * 32 + (quad ^ swz4(row)) * 8]);
        }
        #pragma unroll
        for (int i = 0; i < 2; ++i)
            #pragma unroll
            for (int j = 0; j < 4; ++j)
                acc[i][j] = __builtin_amdgcn_mfma_f32_16x16x32_bf16(af[i], bfr[j], acc[i][j], 0, 0, 0);
        __syncthreads();
        buf ^= 1;
    }

    #pragma unroll
    for (int i = 0; i < 2; ++i) {
        int mbase = m0 + wm + i * 16 + quad * 4;
        #pragma unroll
        for (int j = 0; j < 4; ++j) {
            int n = n0 + wn + j * 16 + lr;
            float bv = bias[n];
            #pragma unroll
            for (int r = 0; r < 4; ++r) {
                int m = mbase + r;
                out[(size_t)m * DIM + n] = acc[i][j][r] + bv;
            }
        }
    }
}

// ---------------- flash attention v10 (restored: best measured, 63.7us) ----------------
// v11 (K->reg): latency-bound, -70%. v12 (QBLK=64): TLP-starved, -50%. Both neighbors
// of v10 in {tile,waves,LDS} space are far worse: v10 is the local optimum.
// Structure: QBLK=32/wave, 4-wave blocks, K dbuf + V tribuf, lagged PV (iter t does
// QK(t) then PV(t-1) in one MFMA cluster; exp(t) is the VALU cluster), direct V
// fragments via qkvv's pre-permuted Vt, XCD-chunked swizzle, setprio on MFMA.
__global__ __launch_bounds__(256, 3) void attn_kernel(
        const bf16* __restrict__ Q, const bf16* __restrict__ Kd,
        const bf16* __restrict__ Vt, bf16* __restrict__ Ab)
{
    __shared__ __align__(16) bf16 SH[5 * 64 * 64];   // K dbuf (2x8KB) + V tribuf (3x8KB)
    bf16* Kb = SH;
    bf16* Vb = SH + 2 * 4096;

    const int tid  = threadIdx.x;

    // XCD-chunked bijective remap (nwg=768, chunk=96)
    const int dd = blockIdx.x + 16 * blockIdx.y;   // 0..767
    const int L  = (dd & 7) * 96 + (dd >> 3);
    const int bh = L >> 4;
    const int q0 = (L & 15) * 128;

    const int b    = bh / HEADS, h = bh % HEADS;
    const int lane = tid & 63, w = tid >> 6;
    const int l31  = lane & 31, hw = lane >> 5;
    const int wq   = w * 32;

    const size_t qkbase = (size_t)bh * SEQ * HDIM;
    const size_t vbase  = (size_t)h * HDIM * MROWS + (size_t)b * SEQ;

    const int src_row  = tid >> 3, src_ch = tid & 7;
    const int src_gch  = src_ch ^ (src_row & 7);
    const int src_row2 = (tid + 256) >> 3;
    const int src_gch2 = src_ch ^ (src_row2 & 7);
    const int loff1 = src_row  * 64 + src_ch * 8;
    const int loff2 = src_row2 * 64 + src_ch * 8;

    {   // Q (16KB) -> Vb[1..2] (consumed into qf before iter0's V(1) prefetch lands there)
        bf16* Qst = Vb + 4096;
        #pragma unroll
        for (int i = 0; i < 4; ++i) {
            int c = tid + i * 256;
            int row = c >> 3, ch = c & 7;
            int gch = ch ^ (row & 7);
            gload_lds16(Q + qkbase + (size_t)(q0 + row) * HDIM + gch * 8, Qst + row * 64 + ch * 8);
        }
    }

    const bf16* kp1 = Kd + qkbase + (size_t)src_row  * HDIM + src_gch  * 8;
    const bf16* kp2 = Kd + qkbase + (size_t)src_row2 * HDIM + src_gch2 * 8;
    const bf16* vp1 = Vt + vbase  + (size_t)src_row  * MROWS + src_gch  * 8;
    const bf16* vp2 = Vt + vbase  + (size_t)src_row2 * MROWS + src_gch2 * 8;
    const ptrdiff_t kstep = 64 * HDIM, vstep = 64;

    gload_lds16(kp1, Kb + loff1); gload_lds16(kp2, Kb + loff2);
    gload_lds16(vp1, Vb + loff1); gload_lds16(vp2, Vb + loff2);
    __syncthreads();

    bf16x8_t qf[4];
    {
        const bf16* Qst = Vb + 4096;
        int row = wq + l31;
        #pragma unroll
        for (int g = 0; g < 4; ++g) {
            int ch = (2 * g + hw) ^ (row & 7);
            qf[g] = *reinterpret_cast<const bf16x8_t*>(&Qst[row * 64 + ch * 8]);
        }
    }
    __syncthreads();

    f32x16_t oacc[2] = {};
    f32x16_t rsacc  = {};
    bf16x8_t pk[4];
    bf16x8_t ones8;
    #pragma unroll
    for (int i = 0; i < 8; ++i) ones8[i] = (bf16)1.0f;

    int vprev = 2, vcur = 0, vnext = 1;
    const int NT = SEQ / 64;

    for (int it = 0; it < NT; ++it) {
        if (it + 1 < NT) {
            const ptrdiff_t g = (ptrdiff_t)(it + 1);
            bf16* kd = Kb + ((it + 1) & 1) * 4096;
            bf16* vd = Vb + vnext * 4096;
            gload_lds16(kp1 + g * kstep, kd + loff1); gload_lds16(kp2 + g * kstep, kd + loff2);
            gload_lds16(vp1 + g * vstep, vd + loff1); gload_lds16(vp2 + g * vstep, vd + loff2);
        }

        const bf16* Ks = Kb + (it & 1) * 4096;

        f32x16_t sacc[2] = {};
        __builtin_amdgcn_s_setprio(1);
        #pragma unroll
        for (int kc = 0; kc < 2; ++kc) {
            int row = kc * 32 + l31;
            #pragma unroll
            for (int g = 0; g < 4; ++g) {
                int ch = (2 * g + hw) ^ (row & 7);
                bf16x8_t af = *reinterpret_cast<const bf16x8_t*>(&Ks[row * 64 + ch * 8]);
                sacc[kc] = __builtin_amdgcn_mfma_f32_32x32x16_bf16(af, qf[g], sacc[kc], 0, 0, 0);
            }
        }

        if (it > 0) {   // PV(t-1) + rsacc(t-1): same MFMA cluster as QK(t)
            const bf16* Vs = Vb + vprev * 4096;
            #pragma unroll
            for (int dc = 0; dc < 2; ++dc) {
                int row = dc * 32 + l31;
                #pragma unroll
                for (int kg = 0; kg < 4; ++kg) {
                    int myc = (2 * kg + hw) ^ (row & 7);
                    bf16x8_t bb = *reinterpret_cast<const bf16x8_t*>(&Vs[row * 64 + myc * 8]);
                    oacc[dc] = __builtin_amdgcn_mfma_f32_32x32x16_bf16(pk[kg], bb, oacc[dc], 0, 0, 0);
                }
            }
            #pragma unroll
            for (int kg = 0; kg < 4; ++kg)
                rsacc = __builtin_amdgcn_mfma_f32_32x32x16_bf16(pk[kg], ones8, rsacc, 0, 0, 0);
        }
        __builtin_amdgcn_s_setprio(0);

        #pragma unroll
        for (int kg = 0; kg < 4; ++kg) {
            #pragma unroll
            for (int j = 0; j < 8; ++j)
                pk[kg][j] = (bf16)__builtin_amdgcn_exp2f(sacc[kg >> 1][(kg & 1) * 8 + j]);
        }

        __syncthreads();
        int tmp = vprev; vprev = vcur; vcur = vnext; vnext = tmp;
    }

    {   // epilogue: PV(last) + rsacc(last)
        const bf16* Vs = Vb + vprev * 4096;
        #pragma unroll
        for (int dc = 0; dc < 2; ++dc) {
            int row = dc * 32 + l31;
            #pragma unroll
            for (int kg = 0; kg < 4; ++kg) {
                int myc = (2 * kg + hw) ^ (row & 7);
                bf16x8_t bb = *reinterpret_cast<const bf16x8_t*>(&Vs[row * 64 + myc * 8]);
                oacc[dc] = __builtin_amdgcn_mfma_f32_32x32x16_bf16(pk[kg], bb, oacc[dc], 0, 0, 0);
            }
        }
        #pragma unroll
        for (int kg = 0; kg < 4; ++kg)
            rsacc = __builtin_amdgcn_mfma_f32_32x32x16_bf16(pk[kg], ones8, rsacc, 0, 0, 0);
    }

    float inv[16];
    #pragma unroll
    for (int r = 0; r < 16; ++r)
        inv[r] = 1.0f / rsacc[r];
    #pragma unroll
    for (int dc = 0; dc < 2; ++dc) {
        int d = dc * 32 + l31;
        #pragma unroll
        for (int r = 0; r < 16; ++r) {
            int q = q0 + wq + (r & 3) + 8 * (r >> 2) + 4 * hw;
            Ab[((size_t)b * SEQ + q) * DIM + h * HDIM + d] = (bf16)(oacc[dc][r] * inv[r]);
        }
    }
}

extern "C" void kernel_launch(void* const* d_in, const int* in_sizes, int n_in,
                              void* d_out, int out_size, void* d_ws, size_t ws_size,
                              hipStream_t stream) {
    (void)in_sizes; (void)n_in; (void)out_size; (void)ws_size;
    const float* x  = (const float*)d_in[0];
    const float* Wq = (const float*)d_in[1];
    const float* Wk = (const float*)d_in[2];
    const float* Wv = (const float*)d_in[3];
    const float* Wp = (const float*)d_in[4];
    const float* bp = (const float*)d_in[5];
    float* out = (float*)d_out;

    char* ws = (char*)d_ws;
    size_t off = 0;
    auto alloc = [&](size_t bytes) {
        void* p = ws + off;
        off += (bytes + 255) & ~(size_t)255;
        return p;
    };
    const size_t big = (size_t)MROWS * DIM * sizeof(bf16);
    const size_t wsz = (size_t)DIM * DIM * sizeof(bf16);
    bf16* Xb  = (bf16*)alloc(big);
    bf16* Qb  = (bf16*)alloc(big);
    bf16* Kb  = (bf16*)alloc(big);
    bf16* Vtb = (bf16*)alloc(big);
    bf16* Wqb = (bf16*)alloc(wsz);
    bf16* Wkb = (bf16*)alloc(wsz);
    bf16* Wvb = (bf16*)alloc(wsz);
    bf16* Wpb = (bf16*)alloc(wsz);
    bf16* Ab  = Xb;   // Xb dead after projections

    cast_all_kernel<<<(ALL4 + 255) / 256, 256, 0, stream>>>(
        x, Wq, Wk, Wv, Wp, Xb, Wqb, Wkb, Wvb, Wpb);

    qkvv_gemm<<<dim3(DIM / 128, MROWS / 128, 3), 256, 0, stream>>>(
        Xb, Wqb, Wkb, Wvb, Qb, Kb, Vtb);

    attn_kernel<<<dim3(SEQ / 128, BATCH * HEADS), 256, 0, stream>>>(Qb, Kb, Vtb, Ab);

    out_gemm<<<dim3(DIM / 128, MROWS / 64), 256, 0, stream>>>(Ab, Wpb, bp, out);
}

// Round 10
// 215.717 us; speedup vs baseline: 1.1734x; 1.0066x over previous
//
#include <hip/hip_runtime.h>
#include <cstdint>

#define DIM   768
#define HEADS 12
#define HDIM  64
#define BATCH 4
#define SEQ   2048
#define MROWS (BATCH*SEQ)   // 8192

typedef __bf16 bf16;
typedef __bf16 bf16x4_t __attribute__((ext_vector_type(4)));
typedef __bf16 bf16x8_t __attribute__((ext_vector_type(8)));
typedef float  f32x4_t  __attribute__((ext_vector_type(4)));
typedef float  f32x16_t __attribute__((ext_vector_type(16)));

#define X4   (MROWS * DIM / 4)
#define W4   (DIM * DIM / 4)
#define ALL4 (X4 + 4 * W4)

// ---------------- merged fp32 -> bf16 cast (x + 4 weights, one launch) ----------------
__global__ void cast_all_kernel(const float* __restrict__ x,
                                const float* __restrict__ w0, const float* __restrict__ w1,
                                const float* __restrict__ w2, const float* __restrict__ w3,
                                bf16* __restrict__ xd,
                                bf16* __restrict__ d0, bf16* __restrict__ d1,
                                bf16* __restrict__ d2, bf16* __restrict__ d3) {
    int i = blockIdx.x * blockDim.x + threadIdx.x;
    if (i >= ALL4) return;
    const float* src; bf16* dst; int j;
    if (i < X4) { src = x; dst = xd; j = i; }
    else {
        int t = i - X4;  int y = t / W4;  j = t - y * W4;
        src = (y == 0) ? w0 : (y == 1) ? w1 : (y == 2) ? w2 : w3;
        dst = (y == 0) ? d0 : (y == 1) ? d1 : (y == 2) ? d2 : d3;
    }
    const float4 v = reinterpret_cast<const float4*>(src)[j];
    bf16x4_t o;
    o[0] = (bf16)v.x; o[1] = (bf16)v.y; o[2] = (bf16)v.z; o[3] = (bf16)v.w;
    reinterpret_cast<bf16x4_t*>(dst)[j] = o;
}

// async global->LDS, 16B per lane. LDS dest is wave-uniform base + lane*16.
__device__ __forceinline__ void gload_lds16(const bf16* g, bf16* l) {
    __builtin_amdgcn_global_load_lds((const __attribute__((address_space(1))) void*)g,
                                     (__attribute__((address_space(3))) void*)l, 16, 0, 0);
}

// chunk swizzle for BK=32 rows (4 chunks of 16B): <=2-way bank residue on b128 reads
__device__ __forceinline__ int swz4(int row) { return (row & 3) ^ ((row >> 2) & 3); }

// ---------------- merged projection GEMM v5: z-FUSED (Q,K,V in one block) --------------
// The three z-slices shared the same X B-operand but each re-staged and re-read it.
// Fused: per phase stage {Wq,Wk,Wv,X} (32KB for 192 block-MFMAs = 171B/MFMA, was
// 256B/MFMA) and read bfr once for all 3 accumulator sets (0.33 ds_read/MFMA, was
// 0.5) -> phases become MFMA-bound. LDS 64KB dbuf = 2 blocks/CU; acc 3x[4][4] =
// 192 VGPR -> launch_bounds(256,2). Grid 384 = 8 XCDs x 48 (X 1.5MB + W 3.5MB per
// XCD ~ L2). Epilogues: Q (scaled), K packed bf16x4; Vt via LDS involution tile.
__global__ __launch_bounds__(256, 2) void qkvv_gemm(
        const bf16* __restrict__ X,
        const bf16* __restrict__ Wq, const bf16* __restrict__ Wk, const bf16* __restrict__ Wv,
        bf16* __restrict__ Q, bf16* __restrict__ Kd, bf16* __restrict__ Vt)
{
    __shared__ __align__(16) bf16 SM[2][4][128 * 32];   // [buf][Wq|Wk|Wv|X][row*32] = 64KB
    const int tid  = threadIdx.x;

    // XCD-chunked bijective remap (nwg=384, chunk=48), m-major within chunk
    const int d  = blockIdx.x + 6 * blockIdx.y;    // 0..383
    const int L  = (d & 7) * 48 + (d >> 3);
    const int m0 = (L % 6) * 128;                  // dfull
    const int n0 = (L / 6) * 128;                  // sample

    const int lane = tid & 63;
    const int w    = tid >> 6;
    const int wm   = (w & 1) * 64, wn = (w >> 1) * 64;
    const int lr   = lane & 15, quad = lane >> 4;

    // staging: 512 chunks per tile, 2 per thread per tile, linear LDS dest
    const int sr1 = tid >> 2, sc1 = tid & 3;
    const int sr2 = (tid + 256) >> 2;
    const int g1 = sc1 ^ swz4(sr1);
    const int g2 = sc1 ^ swz4(sr2);

    f32x4_t acc[3][4][4] = {};

    #define STAGE(B, KK)                                                                   \
        {   int kk_ = (KK);                                                                \
            gload_lds16(Wq + (size_t)(m0 + sr1) * DIM + kk_ + g1 * 8, &SM[B][0][tid * 8]); \
            gload_lds16(Wk + (size_t)(m0 + sr1) * DIM + kk_ + g1 * 8, &SM[B][1][tid * 8]); \
            gload_lds16(Wv + (size_t)(m0 + sr1) * DIM + kk_ + g1 * 8, &SM[B][2][tid * 8]); \
            gload_lds16(X  + (size_t)(n0 + sr1) * DIM + kk_ + g1 * 8, &SM[B][3][tid * 8]); \
            gload_lds16(Wq + (size_t)(m0 + sr2) * DIM + kk_ + g2 * 8, &SM[B][0][(tid + 256) * 8]); \
            gload_lds16(Wk + (size_t)(m0 + sr2) * DIM + kk_ + g2 * 8, &SM[B][1][(tid + 256) * 8]); \
            gload_lds16(Wv + (size_t)(m0 + sr2) * DIM + kk_ + g2 * 8, &SM[B][2][(tid + 256) * 8]); \
            gload_lds16(X  + (size_t)(n0 + sr2) * DIM + kk_ + g2 * 8, &SM[B][3][(tid + 256) * 8]); \
        }

    STAGE(0, 0);
    __syncthreads();

    int buf = 0;
    for (int p = 0; p < DIM / 32; ++p) {
        if (p + 1 < DIM / 32) {
            if (buf) STAGE(0, (p + 1) * 32) else STAGE(1, (p + 1) * 32);
        }
        bf16x8_t bfr[4];
        #pragma unroll
        for (int j = 0; j < 4; ++j) {
            int row = wn + j * 16 + lr;
            bfr[j] = *reinterpret_cast<const bf16x8_t*>(&SM[buf][3][row * 32 + (quad ^ swz4(row)) * 8]);
        }
        #pragma unroll
        for (int z = 0; z < 3; ++z) {
            bf16x8_t af[4];
            #pragma unroll
            for (int i = 0; i < 4; ++i) {
                int row = wm + i * 16 + lr;
                af[i] = *reinterpret_cast<const bf16x8_t*>(&SM[buf][z][row * 32 + (quad ^ swz4(row)) * 8]);
            }
            #pragma unroll
            for (int i = 0; i < 4; ++i)
                #pragma unroll
                for (int j = 0; j < 4; ++j)
                    acc[z][i][j] = __builtin_amdgcn_mfma_f32_16x16x32_bf16(af[i], bfr[j], acc[z][i][j], 0, 0, 0);
        }
        __syncthreads();            // drains vmcnt (prefetch) + seals buf swap
        buf ^= 1;
    }
    #undef STAGE

    // ---- epilogue: Q (scaled) and K packed stores ----
    #pragma unroll
    for (int z = 0; z < 2; ++z) {
        const float sc = (z == 0) ? 0.18033688011112042f : 1.0f;   // log2(e)/8 into Q
        bf16* dst = (z == 0) ? Q : Kd;
        #pragma unroll
        for (int i = 0; i < 4; ++i) {
            int mb = m0 + wm + i * 16 + quad * 4;
            int h  = mb >> 6, d0 = mb & 63;
            #pragma unroll
            for (int j = 0; j < 4; ++j) {
                int sample = n0 + wn + j * 16 + lr;
                int b = sample >> 11, srow = sample & 2047;
                bf16x4_t o;
                #pragma unroll
                for (int r = 0; r < 4; ++r)
                    o[r] = (bf16)(acc[z][i][j][r] * sc);
                *reinterpret_cast<bf16x4_t*>(
                    &dst[(((size_t)b * HEADS + h) * SEQ + srow) * HDIM + d0]) = o;
            }
        }
    }

    // ---- epilogue: Vt via LDS C-tile with piece involution {0,2,1,3}, b128 rows ----
    {
        bf16* CT = &SM[0][0][0];   // 32KB, free after last K-loop barrier
        #pragma unroll
        for (int i = 0; i < 4; ++i) {
            int ml = wm + i * 16 + quad * 4;
            #pragma unroll
            for (int j = 0; j < 4; ++j) {
                int pc  = lr >> 2;
                int pp  = ((pc & 1) << 1) | (pc >> 1);           // 0,2,1,3
                int nl  = wn + j * 16 + (pp << 2) + (lr & 3);
                #pragma unroll
                for (int r = 0; r < 4; ++r)
                    CT[(ml + r) * 128 + nl] = (bf16)acc[2][i][j][r];
            }
        }
        __syncthreads();
        const int rr = tid >> 4, cc = tid & 15;
        #pragma unroll
        for (int rnd = 0; rnd < 8; ++rnd) {
            int ml = rnd * 16 + rr;
            *reinterpret_cast<bf16x8_t*>(&Vt[(size_t)(m0 + ml) * MROWS + n0 + cc * 8]) =
                *reinterpret_cast<const bf16x8_t*>(&CT[ml * 128 + cc * 8]);
        }
    }
}

// ---------------- output projection GEMM v2: prefetch + dbuf (BK=32, 24 phases) --------
__global__ __launch_bounds__(256, 4) void out_gemm(
        const bf16* __restrict__ A,       // [8192,768]
        const bf16* __restrict__ W,       // [768,768]
        const float* __restrict__ bias,
        float* __restrict__ out)          // [8192,768] f32
{
    __shared__ __align__(16) bf16 SA[2][64 * 32];    // 2x4KB
    __shared__ __align__(16) bf16 SB[2][128 * 32];   // 2x8KB
    const int tid  = threadIdx.x;

    const int d  = blockIdx.x + 6 * blockIdx.y;   // 0..767
    const int L  = (d & 7) * 96 + (d >> 3);
    const int n0 = (L % 6) * 128;
    const int m0 = (L / 6) * 64;

    const int lane = tid & 63;
    const int w    = tid >> 6;
    const int wm   = (w & 1) * 32, wn = (w >> 1) * 64;
    const int lr   = lane & 15, quad = lane >> 4;

    const int sr1 = tid >> 2, sc1 = tid & 3;
    const int sr2 = (tid + 256) >> 2;
    const int g1 = sc1 ^ swz4(sr1);
    const int g2 = sc1 ^ swz4(sr2);

    f32x4_t acc[2][4] = {};

    {   // prologue: phase 0 into buf 0
        gload_lds16(A + (size_t)(m0 + sr1) * DIM + g1 * 8, &SA[0][tid * 8]);
        gload_lds16(W + (size_t)(n0 + sr1) * DIM + g1 * 8, &SB[0][tid * 8]);
        gload_lds16(W + (size_t)(n0 + sr2) * DIM + g2 * 8, &SB[0][(tid + 256) * 8]);
    }
    __syncthreads();

    int buf = 0;
    for (int p = 0; p < DIM / 32; ++p) {
        if (p + 1 < DIM / 32) {
            int kk = (p + 1) * 32;
            gload_lds16(A + (size_t)(m0 + sr1) * DIM + kk + g1 * 8, &SA[buf ^ 1][tid * 8]);
            gload_lds16(W + (size_t)(n0 + sr1) * DIM + kk + g1 * 8, &SB[buf ^ 1][tid * 8]);
            gload_lds16(W + (size_t)(n0 + sr2) * DIM + kk + g2 * 8, &SB[buf ^ 1][(tid + 256) * 8]);
        }
        bf16x8_t af[2], bfr[4];
        #pragma unroll
        for (int i = 0; i < 2; ++i) {
            int row = wm + i * 16 + lr;
            af[i] = *reinterpret_cast<const bf16x8_t*>(&SA[buf][row * 32 + (quad ^ swz4(row)) * 8]);
        }
        #pragma unroll
        for (int j = 0; j < 4; ++j) {
            int row = wn + j * 16 + lr;
            bfr[j] = *reinterpret_cast<const bf16x8_t*>(&SB[buf][row * 32 + (quad ^ swz4(row)) * 8]);
        }
        #pragma unroll
        for (int i = 0; i < 2; ++i)
            #pragma unroll
            for (int j = 0; j < 4; ++j)
                acc[i][j] = __builtin_amdgcn_mfma_f32_16x16x32_bf16(af[i], bfr[j], acc[i][j], 0, 0, 0);
        __syncthreads();
        buf ^= 1;
    }

    #pragma unroll
    for (int i = 0; i < 2; ++i) {
        int mbase = m0 + wm + i * 16 + quad * 4;
        #pragma unroll
        for (int j = 0; j < 4; ++j) {
            int n = n0 + wn + j * 16 + lr;
            float bv = bias[n];
            #pragma unroll
            for (int r = 0; r < 4; ++r) {
                int m = mbase + r;
                out[(size_t)m * DIM + n] = acc[i][j][r] + bv;
            }
        }
    }
}

// ---------------- flash attention v10 (local optimum; unchanged) ----------------
__global__ __launch_bounds__(256, 3) void attn_kernel(
        const bf16* __restrict__ Q, const bf16* __restrict__ Kd,
        const bf16* __restrict__ Vt, bf16* __restrict__ Ab)
{
    __shared__ __align__(16) bf16 SH[5 * 64 * 64];   // K dbuf (2x8KB) + V tribuf (3x8KB)
    bf16* Kb = SH;
    bf16* Vb = SH + 2 * 4096;

    const int tid  = threadIdx.x;

    // XCD-chunked bijective remap (nwg=768, chunk=96)
    const int dd = blockIdx.x + 16 * blockIdx.y;   // 0..767
    const int L  = (dd & 7) * 96 + (dd >> 3);
    const int bh = L >> 4;
    const int q0 = (L & 15) * 128;

    const int b    = bh / HEADS, h = bh % HEADS;
    const int lane = tid & 63, w = tid >> 6;
    const int l31  = lane & 31, hw = lane >> 5;
    const int wq   = w * 32;

    const size_t qkbase = (size_t)bh * SEQ * HDIM;
    const size_t vbase  = (size_t)h * HDIM * MROWS + (size_t)b * SEQ;

    const int src_row  = tid >> 3, src_ch = tid & 7;
    const int src_gch  = src_ch ^ (src_row & 7);
    const int src_row2 = (tid + 256) >> 3;
    const int src_gch2 = src_ch ^ (src_row2 & 7);
    const int loff1 = src_row  * 64 + src_ch * 8;
    const int loff2 = src_row2 * 64 + src_ch * 8;

    {   // Q (16KB) -> Vb[1..2] (consumed into qf before iter0's V(1) prefetch lands there)
        bf16* Qst = Vb + 4096;
        #pragma unroll
        for (int i = 0; i < 4; ++i) {
            int c = tid + i * 256;
            int row = c >> 3, ch = c & 7;
            int gch = ch ^ (row & 7);
            gload_lds16(Q + qkbase + (size_t)(q0 + row) * HDIM + gch * 8, Qst + row * 64 + ch * 8);
        }
    }

    const bf16* kp1 = Kd + qkbase + (size_t)src_row  * HDIM + src_gch  * 8;
    const bf16* kp2 = Kd + qkbase + (size_t)src_row2 * HDIM + src_gch2 * 8;
    const bf16* vp1 = Vt + vbase  + (size_t)src_row  * MROWS + src_gch  * 8;
    const bf16* vp2 = Vt + vbase  + (size_t)src_row2 * MROWS + src_gch2 * 8;
    const ptrdiff_t kstep = 64 * HDIM, vstep = 64;

    gload_lds16(kp1, Kb + loff1); gload_lds16(kp2, Kb + loff2);
    gload_lds16(vp1, Vb + loff1); gload_lds16(vp2, Vb + loff2);
    __syncthreads();

    bf16x8_t qf[4];
    {
        const bf16* Qst = Vb + 4096;
        int row = wq + l31;
        #pragma unroll
        for (int g = 0; g < 4; ++g) {
            int ch = (2 * g + hw) ^ (row & 7);
            qf[g] = *reinterpret_cast<const bf16x8_t*>(&Qst[row * 64 + ch * 8]);
        }
    }
    __syncthreads();

    f32x16_t oacc[2] = {};
    f32x16_t rsacc  = {};
    bf16x8_t pk[4];
    bf16x8_t ones8;
    #pragma unroll
    for (int i = 0; i < 8; ++i) ones8[i] = (bf16)1.0f;

    int vprev = 2, vcur = 0, vnext = 1;
    const int NT = SEQ / 64;

    for (int it = 0; it < NT; ++it) {
        if (it + 1 < NT) {
            const ptrdiff_t g = (ptrdiff_t)(it + 1);
            bf16* kd = Kb + ((it + 1) & 1) * 4096;
            bf16* vd = Vb + vnext * 4096;
            gload_lds16(kp1 + g * kstep, kd + loff1); gload_lds16(kp2 + g * kstep, kd + loff2);
            gload_lds16(vp1 + g * vstep, vd + loff1); gload_lds16(vp2 + g * vstep, vd + loff2);
        }

        const bf16* Ks = Kb + (it & 1) * 4096;

        f32x16_t sacc[2] = {};
        __builtin_amdgcn_s_setprio(1);
        #pragma unroll
        for (int kc = 0; kc < 2; ++kc) {
            int row = kc * 32 + l31;
            #pragma unroll
            for (int g = 0; g < 4; ++g) {
                int ch = (2 * g + hw) ^ (row & 7);
                bf16x8_t af = *reinterpret_cast<const bf16x8_t*>(&Ks[row * 64 + ch * 8]);
                sacc[kc] = __builtin_amdgcn_mfma_f32_32x32x16_bf16(af, qf[g], sacc[kc], 0, 0, 0);
            }
        }

        if (it > 0) {   // PV(t-1) + rsacc(t-1): same MFMA cluster as QK(t)
            const bf16* Vs = Vb + vprev * 4096;
            #pragma unroll
            for (int dc = 0; dc < 2; ++dc) {
                int row = dc * 32 + l31;
                #pragma unroll
                for (int kg = 0; kg < 4; ++kg) {
                    int myc = (2 * kg + hw) ^ (row & 7);
                    bf16x8_t bb = *reinterpret_cast<const bf16x8_t*>(&Vs[row * 64 + myc * 8]);
                    oacc[dc] = __builtin_amdgcn_mfma_f32_32x32x16_bf16(pk[kg], bb, oacc[dc], 0, 0, 0);
                }
            }
            #pragma unroll
            for (int kg = 0; kg < 4; ++kg)
                rsacc = __builtin_amdgcn_mfma_f32_32x32x16_bf16(pk[kg], ones8, rsacc, 0, 0, 0);
        }
        __builtin_amdgcn_s_setprio(0);

        #pragma unroll
        for (int kg = 0; kg < 4; ++kg) {
            #pragma unroll
            for (int j = 0; j < 8; ++j)
                pk[kg][j] = (bf16)__builtin_amdgcn_exp2f(sacc[kg >> 1][(kg & 1) * 8 + j]);
        }

        __syncthreads();
        int tmp = vprev; vprev = vcur; vcur = vnext; vnext = tmp;
    }

    {   // epilogue: PV(last) + rsacc(last)
        const bf16* Vs = Vb + vprev * 4096;
        #pragma unroll
        for (int dc = 0; dc < 2; ++dc) {
            int row = dc * 32 + l31;
            #pragma unroll
            for (int kg = 0; kg < 4; ++kg) {
                int myc = (2 * kg + hw) ^ (row & 7);
                bf16x8_t bb = *reinterpret_cast<const bf16x8_t*>(&Vs[row * 64 + myc * 8]);
                oacc[dc] = __builtin_amdgcn_mfma_f32_32x32x16_bf16(pk[kg], bb, oacc[dc], 0, 0, 0);
            }
        }
        #pragma unroll
        for (int kg = 0; kg < 4; ++kg)
            rsacc = __builtin_amdgcn_mfma_f32_32x32x16_bf16(pk[kg], ones8, rsacc, 0, 0, 0);
    }

    float inv[16];
    #pragma unroll
    for (int r = 0; r < 16; ++r)
        inv[r] = 1.0f / rsacc[r];
    #pragma unroll
    for (int dc = 0; dc < 2; ++dc) {
        int d = dc * 32 + l31;
        #pragma unroll
        for (int r = 0; r < 16; ++r) {
            int q = q0 + wq + (r & 3) + 8 * (r >> 2) + 4 * hw;
            Ab[((size_t)b * SEQ + q) * DIM + h * HDIM + d] = (bf16)(oacc[dc][r] * inv[r]);
        }
    }
}

extern "C" void kernel_launch(void* const* d_in, const int* in_sizes, int n_in,
                              void* d_out, int out_size, void* d_ws, size_t ws_size,
                              hipStream_t stream) {
    (void)in_sizes; (void)n_in; (void)out_size; (void)ws_size;
    const float* x  = (const float*)d_in[0];
    const float* Wq = (const float*)d_in[1];
    const float* Wk = (const float*)d_in[2];
    const float* Wv = (const float*)d_in[3];
    const float* Wp = (const float*)d_in[4];
    const float* bp = (const float*)d_in[5];
    float* out = (float*)d_out;

    char* ws = (char*)d_ws;
    size_t off = 0;
    auto alloc = [&](size_t bytes) {
        void* p = ws + off;
        off += (bytes + 255) & ~(size_t)255;
        return p;
    };
    const size_t big = (size_t)MROWS * DIM * sizeof(bf16);
    const size_t wsz = (size_t)DIM * DIM * sizeof(bf16);
    bf16* Xb  = (bf16*)alloc(big);
    bf16* Qb  = (bf16*)alloc(big);
    bf16* Kb  = (bf16*)alloc(big);
    bf16* Vtb = (bf16*)alloc(big);
    bf16* Wqb = (bf16*)alloc(wsz);
    bf16* Wkb = (bf16*)alloc(wsz);
    bf16* Wvb = (bf16*)alloc(wsz);
    bf16* Wpb = (bf16*)alloc(wsz);
    bf16* Ab  = Xb;   // Xb dead after projections

    cast_all_kernel<<<(ALL4 + 255) / 256, 256, 0, stream>>>(
        x, Wq, Wk, Wv, Wp, Xb, Wqb, Wkb, Wvb, Wpb);

    qkvv_gemm<<<dim3(6, MROWS / 128), 256, 0, stream>>>(
        Xb, Wqb, Wkb, Wvb, Qb, Kb, Vtb);

    attn_kernel<<<dim3(SEQ / 128, BATCH * HEADS), 256, 0, stream>>>(Qb, Kb, Vtb, Ab);

    out_gemm<<<dim3(DIM / 128, MROWS / 64), 256, 0, stream>>>(Ab, Wpb, bp, out);
}

// Round 12
// 209.656 us; speedup vs baseline: 1.2073x; 1.0289x over previous
//
#include <hip/hip_runtime.h>
#include <cstdint>

#define DIM   768
#define HEADS 12
#define HDIM  64
#define BATCH 4
#define SEQ   2048
#define MROWS (BATCH*SEQ)   // 8192

typedef __bf16 bf16;
typedef __bf16 bf16x4_t __attribute__((ext_vector_type(4)));
typedef __bf16 bf16x8_t __attribute__((ext_vector_type(8)));
typedef float  f32x4_t  __attribute__((ext_vector_type(4)));
typedef float  f32x16_t __attribute__((ext_vector_type(16)));

#define X4   (MROWS * DIM / 4)
#define W4   (DIM * DIM / 4)
#define ALL4 (X4 + 4 * W4)

// ---------------- merged fp32 -> bf16 cast (x + 4 weights, one launch) ----------------
__global__ void cast_all_kernel(const float* __restrict__ x,
                                const float* __restrict__ w0, const float* __restrict__ w1,
                                const float* __restrict__ w2, const float* __restrict__ w3,
                                bf16* __restrict__ xd,
                                bf16* __restrict__ d0, bf16* __restrict__ d1,
                                bf16* __restrict__ d2, bf16* __restrict__ d3) {
    int i = blockIdx.x * blockDim.x + threadIdx.x;
    if (i >= ALL4) return;
    const float* src; bf16* dst; int j;
    if (i < X4) { src = x; dst = xd; j = i; }
    else {
        int t = i - X4;  int y = t / W4;  j = t - y * W4;
        src = (y == 0) ? w0 : (y == 1) ? w1 : (y == 2) ? w2 : w3;
        dst = (y == 0) ? d0 : (y == 1) ? d1 : (y == 2) ? d2 : d3;
    }
    const float4 v = reinterpret_cast<const float4*>(src)[j];
    bf16x4_t o;
    o[0] = (bf16)v.x; o[1] = (bf16)v.y; o[2] = (bf16)v.z; o[3] = (bf16)v.w;
    reinterpret_cast<bf16x4_t*>(dst)[j] = o;
}

// async global->LDS, 16B per lane. LDS dest is wave-uniform base + lane*16.
__device__ __forceinline__ void gload_lds16(const bf16* g, bf16* l) {
    __builtin_amdgcn_global_load_lds((const __attribute__((address_space(1))) void*)g,
                                     (__attribute__((address_space(3))) void*)l, 16, 0, 0);
}

// chunk swizzle for BK=32 rows (4 chunks of 16B): <=2-way bank residue on b128 reads
__device__ __forceinline__ int swz4(int row) { return (row & 3) ^ ((row >> 2) & 3); }

// Drain LDS reads before the next raw barrier (rule #18: compiler may sink the
// MFMA+lgkmcnt below s_barrier, leaving queued ds_reads racing the next STAGE).
__device__ __forceinline__ void lds_drain() {
    asm volatile("s_waitcnt lgkmcnt(0)" ::: "memory");
    __builtin_amdgcn_sched_barrier(0);
}

// ---------------- projection GEMM v6b: split-z + T4 counted-vmcnt tri-buffer -----------
// Raw s_barrier (no vmcnt drain) + counted s_waitcnt vmcnt(4); STAGE(p+2) issued at
// phase p -> prefetch stays in flight ACROSS barriers. Tri-buffer 48KB = 3 blocks/CU.
// v6's race fixed: lds_drain() at end of each phase guarantees ds_reads of buf
// (p)%3 complete before the NEXT phase's barrier lets STAGE(p+3) overwrite it.
__global__ __launch_bounds__(256, 3) void qkvv_gemm(
        const bf16* __restrict__ X,
        const bf16* __restrict__ Wq, const bf16* __restrict__ Wk, const bf16* __restrict__ Wv,
        bf16* __restrict__ Q, bf16* __restrict__ Kd, bf16* __restrict__ Vt)
{
    __shared__ __align__(16) bf16 SM[3][2][128 * 32];   // [buf][A|B][row*32] = 48KB
    const int tid  = threadIdx.x;

    // XCD-chunked bijective remap (nwg=1152, chunk=144)
    const int d  = blockIdx.x + 6 * blockIdx.y + 384 * blockIdx.z;
    const int L  = (d & 7) * 144 + (d >> 3);
    const int z  = L / 384;
    const int rem = L % 384;
    const int m0 = (rem % 6) * 128;   // dfull
    const int n0 = (rem / 6) * 128;   // sample

    const bf16* Ap = (z == 0) ? Wq : (z == 1 ? Wk : Wv);
    const int lane = tid & 63;
    const int w    = tid >> 6;
    const int wm   = (w & 1) * 64, wn = (w >> 1) * 64;
    const int lr   = lane & 15, quad = lane >> 4;

    const int sr1 = tid >> 2, sc1 = tid & 3;
    const int sr2 = (tid + 256) >> 2;
    const int g1 = sc1 ^ swz4(sr1);
    const int g2 = sc1 ^ swz4(sr2);

    f32x4_t acc[4][4] = {};

    #define STAGE(B, KK)                                                                    \
        {   int kk_ = (KK);                                                                 \
            gload_lds16(Ap + (size_t)(m0 + sr1) * DIM + kk_ + g1 * 8, &SM[B][0][tid * 8]);  \
            gload_lds16(X  + (size_t)(n0 + sr1) * DIM + kk_ + g1 * 8, &SM[B][1][tid * 8]);  \
            gload_lds16(Ap + (size_t)(m0 + sr2) * DIM + kk_ + g2 * 8, &SM[B][0][(tid + 256) * 8]); \
            gload_lds16(X  + (size_t)(n0 + sr2) * DIM + kk_ + g2 * 8, &SM[B][1][(tid + 256) * 8]); \
        }

    #define COMPUTE(B)                                                                       \
        {   bf16x8_t af[4], bfr[4];                                                          \
            _Pragma("unroll")                                                                \
            for (int i = 0; i < 4; ++i) {                                                    \
                int row = wm + i * 16 + lr;                                                  \
                af[i] = *reinterpret_cast<const bf16x8_t*>(&SM[B][0][row * 32 + (quad ^ swz4(row)) * 8]); \
            }                                                                                \
            _Pragma("unroll")                                                                \
            for (int j = 0; j < 4; ++j) {                                                    \
                int row = wn + j * 16 + lr;                                                  \
                bfr[j] = *reinterpret_cast<const bf16x8_t*>(&SM[B][1][row * 32 + (quad ^ swz4(row)) * 8]); \
            }                                                                                \
            _Pragma("unroll")                                                                \
            for (int i = 0; i < 4; ++i)                                                      \
                _Pragma("unroll")                                                            \
                for (int j = 0; j < 4; ++j)                                                  \
                    acc[i][j] = __builtin_amdgcn_mfma_f32_16x16x32_bf16(af[i], bfr[j], acc[i][j], 0, 0, 0); \
        }

    STAGE(0, 0);
    STAGE(1, 32);

    for (int p = 0; p < 23; ++p) {
        asm volatile("s_waitcnt vmcnt(4)" ::: "memory");   // STAGE(p) landed; STAGE(p+1) in flight
        __builtin_amdgcn_s_barrier();                      // raw: no drain
        if (p + 2 < 24) STAGE((p + 2) % 3, (p + 2) * 32);
        COMPUTE(p % 3);
        lds_drain();                                       // ds_reads of buf p%3 done before next barrier
    }
    asm volatile("s_waitcnt vmcnt(0)" ::: "memory");       // last tile (STAGE(23))
    __builtin_amdgcn_s_barrier();
    COMPUTE(2);                                            // 23 % 3 == 2
    lds_drain();
    #undef STAGE
    #undef COMPUTE

    if (z == 2) {
        // C-tile via SM[0..1] (32KB contiguous; phase-23 readers used SM[2] - disjoint)
        bf16* CT = &SM[0][0][0];
        #pragma unroll
        for (int i = 0; i < 4; ++i) {
            int ml = wm + i * 16 + quad * 4;
            #pragma unroll
            for (int j = 0; j < 4; ++j) {
                int pc  = lr >> 2;
                int pp  = ((pc & 1) << 1) | (pc >> 1);             // 0,2,1,3
                int nl  = wn + j * 16 + (pp << 2) + (lr & 3);
                #pragma unroll
                for (int r = 0; r < 4; ++r)
                    CT[(ml + r) * 128 + nl] = (bf16)acc[i][j][r];
            }
        }
        __syncthreads();
        const int rr = tid >> 4, cc = tid & 15;
        #pragma unroll
        for (int rnd = 0; rnd < 8; ++rnd) {
            int ml = rnd * 16 + rr;
            *reinterpret_cast<bf16x8_t*>(&Vt[(size_t)(m0 + ml) * MROWS + n0 + cc * 8]) =
                *reinterpret_cast<const bf16x8_t*>(&CT[ml * 128 + cc * 8]);
        }
    } else {
        const float sc = (z == 0) ? 0.18033688011112042f : 1.0f;   // log2(e)/8 into Q
        bf16* dst = (z == 0) ? Q : Kd;
        #pragma unroll
        for (int i = 0; i < 4; ++i) {
            int mb = m0 + wm + i * 16 + quad * 4;
            int h  = mb >> 6, d0 = mb & 63;
            #pragma unroll
            for (int j = 0; j < 4; ++j) {
                int sample = n0 + wn + j * 16 + lr;
                int b = sample >> 11, srow = sample & 2047;
                bf16x4_t o;
                #pragma unroll
                for (int r = 0; r < 4; ++r)
                    o[r] = (bf16)(acc[i][j][r] * sc);
                *reinterpret_cast<bf16x4_t*>(
                    &dst[(((size_t)b * HEADS + h) * SEQ + srow) * HDIM + d0]) = o;
            }
        }
    }
}

// ---------------- output projection GEMM v3b: T4 counted-vmcnt tri-buffer --------------
__global__ __launch_bounds__(256, 4) void out_gemm(
        const bf16* __restrict__ A,       // [8192,768]
        const bf16* __restrict__ W,       // [768,768]
        const float* __restrict__ bias,
        float* __restrict__ out)          // [8192,768] f32
{
    __shared__ __align__(16) bf16 SA[3][64 * 32];    // 12KB
    __shared__ __align__(16) bf16 SB[3][128 * 32];   // 24KB
    const int tid  = threadIdx.x;

    const int d  = blockIdx.x + 6 * blockIdx.y;   // 0..767
    const int L  = (d & 7) * 96 + (d >> 3);
    const int n0 = (L % 6) * 128;
    const int m0 = (L / 6) * 64;

    const int lane = tid & 63;
    const int w    = tid >> 6;
    const int wm   = (w & 1) * 32, wn = (w >> 1) * 64;
    const int lr   = lane & 15, quad = lane >> 4;

    const int sr1 = tid >> 2, sc1 = tid & 3;
    const int sr2 = (tid + 256) >> 2;
    const int g1 = sc1 ^ swz4(sr1);
    const int g2 = sc1 ^ swz4(sr2);

    f32x4_t acc[2][4] = {};

    #define STAGE(B, KK)                                                                    \
        {   int kk_ = (KK);                                                                 \
            gload_lds16(A + (size_t)(m0 + sr1) * DIM + kk_ + g1 * 8, &SA[B][tid * 8]);      \
            gload_lds16(W + (size_t)(n0 + sr1) * DIM + kk_ + g1 * 8, &SB[B][tid * 8]);      \
            gload_lds16(W + (size_t)(n0 + sr2) * DIM + kk_ + g2 * 8, &SB[B][(tid + 256) * 8]); \
        }

    #define COMPUTE(B)                                                                       \
        {   bf16x8_t af[2], bfr[4];                                                          \
            _Pragma("unroll")                                                                \
            for (int i = 0; i < 2; ++i) {                                                    \
                int row = wm + i * 16 + lr;                                                  \
                af[i] = *reinterpret_cast<const bf16x8_t*>(&SA[B][row * 32 + (quad ^ swz4(row)) * 8]); \
            }                                                                                \
            _Pragma("unroll")                                                                \
            for (int j = 0; j < 4; ++j) {                                                    \
                int row = wn + j * 16 + lr;                                                  \
                bfr[j] = *reinterpret_cast<const bf16x8_t*>(&SB[B][row * 32 + (quad ^ swz4(row)) * 8]); \
            }                                                                                \
            _Pragma("unroll")                                                                \
            for (int i = 0; i < 2; ++i)                                                      \
                _Pragma("unroll")                                                            \
                for (int j = 0; j < 4; ++j)                                                  \
                    acc[i][j] = __builtin_amdgcn_mfma_f32_16x16x32_bf16(af[i], bfr[j], acc[i][j], 0, 0, 0); \
        }

    STAGE(0, 0);
    STAGE(1, 32);

    for (int p = 0; p < 23; ++p) {
        asm volatile("s_waitcnt vmcnt(3)" ::: "memory");   // STAGE(p) landed; STAGE(p+1) in flight
        __builtin_amdgcn_s_barrier();
        if (p + 2 < 24) STAGE((p + 2) % 3, (p + 2) * 32);
        COMPUTE(p % 3);
        lds_drain();
    }
    asm volatile("s_waitcnt vmcnt(0)" ::: "memory");
    __builtin_amdgcn_s_barrier();
    COMPUTE(2);
    #undef STAGE
    #undef COMPUTE

    #pragma unroll
    for (int i = 0; i < 2; ++i) {
        int mbase = m0 + wm + i * 16 + quad * 4;
        #pragma unroll
        for (int j = 0; j < 4; ++j) {
            int n = n0 + wn + j * 16 + lr;
            float bv = bias[n];
            #pragma unroll
            for (int r = 0; r < 4; ++r) {
                int m = mbase + r;
                out[(size_t)m * DIM + n] = acc[i][j][r] + bv;
            }
        }
    }
}

// ---------------- flash attention v10 (local optimum; unchanged - clock reference) ------
__global__ __launch_bounds__(256, 3) void attn_kernel(
        const bf16* __restrict__ Q, const bf16* __restrict__ Kd,
        const bf16* __restrict__ Vt, bf16* __restrict__ Ab)
{
    __shared__ __align__(16) bf16 SH[5 * 64 * 64];   // K dbuf (2x8KB) + V tribuf (3x8KB)
    bf16* Kb = SH;
    bf16* Vb = SH + 2 * 4096;

    const int tid  = threadIdx.x;

    // XCD-chunked bijective remap (nwg=768, chunk=96)
    const int dd = blockIdx.x + 16 * blockIdx.y;   // 0..767
    const int L  = (dd & 7) * 96 + (dd >> 3);
    const int bh = L >> 4;
    const int q0 = (L & 15) * 128;

    const int b    = bh / HEADS, h = bh % HEADS;
    const int lane = tid & 63, w = tid >> 6;
    const int l31  = lane & 31, hw = lane >> 5;
    const int wq   = w * 32;

    const size_t qkbase = (size_t)bh * SEQ * HDIM;
    const size_t vbase  = (size_t)h * HDIM * MROWS + (size_t)b * SEQ;

    const int src_row  = tid >> 3, src_ch = tid & 7;
    const int src_gch  = src_ch ^ (src_row & 7);
    const int src_row2 = (tid + 256) >> 3;
    const int src_gch2 = src_ch ^ (src_row2 & 7);
    const int loff1 = src_row  * 64 + src_ch * 8;
    const int loff2 = src_row2 * 64 + src_ch * 8;

    {   // Q (16KB) -> Vb[1..2] (consumed into qf before iter0's V(1) prefetch lands there)
        bf16* Qst = Vb + 4096;
        #pragma unroll
        for (int i = 0; i < 4; ++i) {
            int c = tid + i * 256;
            int row = c >> 3, ch = c & 7;
            int gch = ch ^ (row & 7);
            gload_lds16(Q + qkbase + (size_t)(q0 + row) * HDIM + gch * 8, Qst + row * 64 + ch * 8);
        }
    }

    const bf16* kp1 = Kd + qkbase + (size_t)src_row  * HDIM + src_gch  * 8;
    const bf16* kp2 = Kd + qkbase + (size_t)src_row2 * HDIM + src_gch2 * 8;
    const bf16* vp1 = Vt + vbase  + (size_t)src_row  * MROWS + src_gch  * 8;
    const bf16* vp2 = Vt + vbase  + (size_t)src_row2 * MROWS + src_gch2 * 8;
    const ptrdiff_t kstep = 64 * HDIM, vstep = 64;

    gload_lds16(kp1, Kb + loff1); gload_lds16(kp2, Kb + loff2);
    gload_lds16(vp1, Vb + loff1); gload_lds16(vp2, Vb + loff2);
    __syncthreads();

    bf16x8_t qf[4];
    {
        const bf16* Qst = Vb + 4096;
        int row = wq + l31;
        #pragma unroll
        for (int g = 0; g < 4; ++g) {
            int ch = (2 * g + hw) ^ (row & 7);
            qf[g] = *reinterpret_cast<const bf16x8_t*>(&Qst[row * 64 + ch * 8]);
        }
    }
    __syncthreads();

    f32x16_t oacc[2] = {};
    f32x16_t rsacc  = {};
    bf16x8_t pk[4];
    bf16x8_t ones8;
    #pragma unroll
    for (int i = 0; i < 8; ++i) ones8[i] = (bf16)1.0f;

    int vprev = 2, vcur = 0, vnext = 1;
    const int NT = SEQ / 64;

    for (int it = 0; it < NT; ++it) {
        if (it + 1 < NT) {
            const ptrdiff_t g = (ptrdiff_t)(it + 1);
            bf16* kd = Kb + ((it + 1) & 1) * 4096;
            bf16* vd = Vb + vnext * 4096;
            gload_lds16(kp1 + g * kstep, kd + loff1); gload_lds16(kp2 + g * kstep, kd + loff2);
            gload_lds16(vp1 + g * vstep, vd + loff1); gload_lds16(vp2 + g * vstep, vd + loff2);
        }

        const bf16* Ks = Kb + (it & 1) * 4096;

        f32x16_t sacc[2] = {};
        __builtin_amdgcn_s_setprio(1);
        #pragma unroll
        for (int kc = 0; kc < 2; ++kc) {
            int row = kc * 32 + l31;
            #pragma unroll
            for (int g = 0; g < 4; ++g) {
                int ch = (2 * g + hw) ^ (row & 7);
                bf16x8_t af = *reinterpret_cast<const bf16x8_t*>(&Ks[row * 64 + ch * 8]);
                sacc[kc] = __builtin_amdgcn_mfma_f32_32x32x16_bf16(af, qf[g], sacc[kc], 0, 0, 0);
            }
        }

        if (it > 0) {   // PV(t-1) + rsacc(t-1): same MFMA cluster as QK(t)
            const bf16* Vs = Vb + vprev * 4096;
            #pragma unroll
            for (int dc = 0; dc < 2; ++dc) {
                int row = dc * 32 + l31;
                #pragma unroll
                for (int kg = 0; kg < 4; ++kg) {
                    int myc = (2 * kg + hw) ^ (row & 7);
                    bf16x8_t bb = *reinterpret_cast<const bf16x8_t*>(&Vs[row * 64 + myc * 8]);
                    oacc[dc] = __builtin_amdgcn_mfma_f32_32x32x16_bf16(pk[kg], bb, oacc[dc], 0, 0, 0);
                }
            }
            #pragma unroll
            for (int kg = 0; kg < 4; ++kg)
                rsacc = __builtin_amdgcn_mfma_f32_32x32x16_bf16(pk[kg], ones8, rsacc, 0, 0, 0);
        }
        __builtin_amdgcn_s_setprio(0);

        #pragma unroll
        for (int kg = 0; kg < 4; ++kg) {
            #pragma unroll
            for (int j = 0; j < 8; ++j)
                pk[kg][j] = (bf16)__builtin_amdgcn_exp2f(sacc[kg >> 1][(kg & 1) * 8 + j]);
        }

        __syncthreads();
        int tmp = vprev; vprev = vcur; vcur = vnext; vnext = tmp;
    }

    {   // epilogue: PV(last) + rsacc(last)
        const bf16* Vs = Vb + vprev * 4096;
        #pragma unroll
        for (int dc = 0; dc < 2; ++dc) {
            int row = dc * 32 + l31;
            #pragma unroll
            for (int kg = 0; kg < 4; ++kg) {
                int myc = (2 * kg + hw) ^ (row & 7);
                bf16x8_t bb = *reinterpret_cast<const bf16x8_t*>(&Vs[row * 64 + myc * 8]);
                oacc[dc] = __builtin_amdgcn_mfma_f32_32x32x16_bf16(pk[kg], bb, oacc[dc], 0, 0, 0);
            }
        }
        #pragma unroll
        for (int kg = 0; kg < 4; ++kg)
            rsacc = __builtin_amdgcn_mfma_f32_32x32x16_bf16(pk[kg], ones8, rsacc, 0, 0, 0);
    }

    float inv[16];
    #pragma unroll
    for (int r = 0; r < 16; ++r)
        inv[r] = 1.0f / rsacc[r];
    #pragma unroll
    for (int dc = 0; dc < 2; ++dc) {
        int d = dc * 32 + l31;
        #pragma unroll
        for (int r = 0; r < 16; ++r) {
            int q = q0 + wq + (r & 3) + 8 * (r >> 2) + 4 * hw;
            Ab[((size_t)b * SEQ + q) * DIM + h * HDIM + d] = (bf16)(oacc[dc][r] * inv[r]);
        }
    }
}

extern "C" void kernel_launch(void* const* d_in, const int* in_sizes, int n_in,
                              void* d_out, int out_size, void* d_ws, size_t ws_size,
                              hipStream_t stream) {
    (void)in_sizes; (void)n_in; (void)out_size; (void)ws_size;
    const float* x  = (const float*)d_in[0];
    const float* Wq = (const float*)d_in[1];
    const float* Wk = (const float*)d_in[2];
    const float* Wv = (const float*)d_in[3];
    const float* Wp = (const float*)d_in[4];
    const float* bp = (const float*)d_in[5];
    float* out = (float*)d_out;

    char* ws = (char*)d_ws;
    size_t off = 0;
    auto alloc = [&](size_t bytes) {
        void* p = ws + off;
        off += (bytes + 255) & ~(size_t)255;
        return p;
    };
    const size_t big = (size_t)MROWS * DIM * sizeof(bf16);
    const size_t wsz = (size_t)DIM * DIM * sizeof(bf16);
    bf16* Xb  = (bf16*)alloc(big);
    bf16* Qb  = (bf16*)alloc(big);
    bf16* Kb  = (bf16*)alloc(big);
    bf16* Vtb = (bf16*)alloc(big);
    bf16* Wqb = (bf16*)alloc(wsz);
    bf16* Wkb = (bf16*)alloc(wsz);
    bf16* Wvb = (bf16*)alloc(wsz);
    bf16* Wpb = (bf16*)alloc(wsz);
    bf16* Ab  = Xb;   // Xb dead after projections

    cast_all_kernel<<<(ALL4 + 255) / 256, 256, 0, stream>>>(
        x, Wq, Wk, Wv, Wp, Xb, Wqb, Wkb, Wvb, Wpb);

    qkvv_gemm<<<dim3(DIM / 128, MROWS / 128, 3), 256, 0, stream>>>(
        Xb, Wqb, Wkb, Wvb, Qb, Kb, Vtb);

    attn_kernel<<<dim3(SEQ / 128, BATCH * HEADS), 256, 0, stream>>>(Qb, Kb, Vtb, Ab);

    out_gemm<<<dim3(DIM / 128, MROWS / 64), 256, 0, stream>>>(Ab, Wpb, bp, out);
}